// Round 7
// baseline (1445.724 us; speedup 1.0000x reference)
//
#include <hip/hip_runtime.h>
#include <hip/hip_bf16.h>
#include <math.h>

// ---------------- bucketed CSR build ----------------
// bucket b = dst >> 8 (256 nodes/bucket). Random-scatter writes are confined to
// per-bucket append regions / contiguous csr spans -> near-compulsory HBM traffic
// (R6: k_scatter wrote 105MB for a 6.4MB array = 16x line amplification).

__global__ __launch_bounds__(256) void k_bhist(const int* __restrict__ dst, int* __restrict__ bcnt, int E) {
    __shared__ int h[512];
    int t = threadIdx.x;
    for (int i = t; i < 512; i += 256) h[i] = 0;
    __syncthreads();
    int step = gridDim.x * 256;
    for (int i = blockIdx.x * 256 + t; i < E; i += step) atomicAdd(&h[dst[i] >> 8], 1);
    __syncthreads();
    for (int i = t; i < 512; i += 256) if (h[i]) atomicAdd(&bcnt[i], h[i]);
}

__global__ __launch_bounds__(512) void k_scanBkt(const int* __restrict__ bcnt, int* __restrict__ boff,
                                                 int* __restrict__ bcur, int nb, int E) {
    __shared__ int s[512];
    int t = threadIdx.x;
    int v = (t < nb) ? bcnt[t] : 0;
    s[t] = v;
    __syncthreads();
    for (int off = 1; off < 512; off <<= 1) {
        int x = (t >= off) ? s[t - off] : 0;
        __syncthreads();
        s[t] += x;
        __syncthreads();
    }
    if (t < nb) { boff[t] = s[t] - v; bcur[t] = s[t] - v; }
    if (t == 0) boff[nb] = E;
}

__global__ __launch_bounds__(256) void k_part(const int* __restrict__ src, const int* __restrict__ dst,
                                              int* __restrict__ bcur, uint2* __restrict__ ebuf, int E) {
    int i = blockIdx.x * 256 + threadIdx.x;
    if (i < E) {
        int d = dst[i];
        int pos = atomicAdd(&bcur[d >> 8], 1);
        ebuf[pos] = make_uint2((unsigned)src[i], (unsigned)d);
    }
}

__global__ __launch_bounds__(256) void k_cnt(const uint2* __restrict__ ebuf, const int* __restrict__ boff,
                                             int* __restrict__ cnt, int N) {
    __shared__ int h[256];
    int b = blockIdx.x, t = threadIdx.x;
    h[t] = 0;
    __syncthreads();
    int beg = boff[b], end = boff[b + 1];
    for (int e = beg + t; e < end; e += 256) atomicAdd(&h[ebuf[e].y & 255], 1);
    __syncthreads();
    int node = (b << 8) + t;
    if (node < N) cnt[node] = h[t];
}

__global__ __launch_bounds__(256) void k_scanA(const int* __restrict__ cnt, int* __restrict__ bsum, int N) {
    __shared__ int s[256];
    int t = threadIdx.x;
    int i = blockIdx.x * 256 + t;
    s[t] = (i < N) ? cnt[i] : 0;
    __syncthreads();
    for (int off = 128; off > 0; off >>= 1) {
        if (t < off) s[t] += s[t + off];
        __syncthreads();
    }
    if (t == 0) bsum[blockIdx.x] = s[0];
}

__global__ __launch_bounds__(512) void k_scanB(int* __restrict__ bsum, int B) {
    __shared__ int s[512];
    int t = threadIdx.x;
    int v = (t < B) ? bsum[t] : 0;
    s[t] = v;
    __syncthreads();
    for (int off = 1; off < 512; off <<= 1) {
        int x = (t >= off) ? s[t - off] : 0;
        __syncthreads();
        s[t] += x;
        __syncthreads();
    }
    if (t < B) bsum[t] = s[t] - v;   // exclusive
}

__global__ __launch_bounds__(256) void k_scanC(const int* __restrict__ cnt, const int* __restrict__ bsum,
                                               int* __restrict__ row_off, float* __restrict__ dinv, int N, int E) {
    __shared__ int s[256];
    int t = threadIdx.x;
    int i = blockIdx.x * 256 + t;
    int v = (i < N) ? cnt[i] : 0;
    s[t] = v;
    __syncthreads();
    for (int off = 1; off < 256; off <<= 1) {
        int x = (t >= off) ? s[t - off] : 0;
        __syncthreads();
        s[t] += x;
        __syncthreads();
    }
    if (i < N) {
        int excl = bsum[blockIdx.x] + s[t] - v;
        row_off[i] = excl;
        dinv[i]    = rsqrtf((float)(v > 1 ? v : 1));
    }
    if (i == 0) row_off[N] = E;
}

__global__ __launch_bounds__(256) void k_scat2(const uint2* __restrict__ ebuf, const int* __restrict__ boff,
                                               const int* __restrict__ row_off, int* __restrict__ csr, int N) {
    __shared__ int cur[256];
    int b = blockIdx.x, t = threadIdx.x;
    int node = (b << 8) + t;
    cur[t] = (node < N) ? row_off[node] : 0;
    __syncthreads();
    int beg = boff[b], end = boff[b + 1];
    for (int e = beg + t; e < end; e += 256) {
        uint2 ed = ebuf[e];
        int pos = atomicAdd(&cur[ed.y & 255], 1);
        csr[pos] = (int)ed.x;
    }
}

// ---------------- Chebyshev aggregation: out = alpha * (dinv[n] * sum_j X[j]*dinv[j]) + beta * Z[n] ----------------

template <int D>
__global__ __launch_bounds__(256) void k_aggr(const float* __restrict__ X, const float* __restrict__ Z,
                                              const float* __restrict__ dinv,
                                              const int* __restrict__ row_off, const int* __restrict__ csr,
                                              float* __restrict__ out, float alpha, float beta, int N) {
    int t = blockIdx.x * blockDim.x + threadIdx.x;
    int node = t / D;
    int d = t % D;
    if (node >= N) return;
    int beg = row_off[node], end = row_off[node + 1];
    float a0 = 0.f, a1 = 0.f, a2 = 0.f, a3 = 0.f;
    int j = beg;
    for (; j + 3 < end; j += 4) {
        int s0 = csr[j], s1 = csr[j + 1], s2 = csr[j + 2], s3 = csr[j + 3];
        a0 += X[s0 * D + d] * dinv[s0];
        a1 += X[s1 * D + d] * dinv[s1];
        a2 += X[s2 * D + d] * dinv[s2];
        a3 += X[s3 * D + d] * dinv[s3];
    }
    for (; j < end; ++j) {
        int s = csr[j];
        a0 += X[s * D + d] * dinv[s];
    }
    float acc = (a0 + a1) + (a2 + a3);
    float v = alpha * dinv[node] * acc;
    if (Z) v += beta * Z[node * D + d];
    out[node * D + d] = v;
}

// ---------------- Cheb matmul, LDS-tiled GEMM (unroll capped: R5 full-unroll spilled) ----------------

template <int KDIM>
__global__ __launch_bounds__(256) void k_cheb_t(const float* __restrict__ X0, const float* __restrict__ X1,
                                                const float* __restrict__ X2, const float* __restrict__ W,
                                                const float* __restrict__ b, float* __restrict__ out, int N) {
    __shared__ float Ws[3 * KDIM * 64];
    __shared__ float Xs[KDIM * 65];
    int t = threadIdx.x;
    for (int idx = t; idx < 3 * KDIM * 64; idx += 256) Ws[idx] = W[idx];

    int nbase = blockIdx.x * 64;
    int ln0 = t & 31;
    int ln1 = 32 + ln0;
    int c0  = (t >> 5) * 8;

    int sn  = t & 63;
    int sk0 = (t >> 6) * (KDIM / 4);
    int gn  = nbase + sn; if (gn >= N) gn = N - 1;

    float a0[8], a1[8];
#pragma unroll
    for (int i = 0; i < 8; ++i) { a0[i] = 0.f; a1[i] = 0.f; }

    const float* Xp[3] = { X0, X1, X2 };
#pragma unroll 1
    for (int a = 0; a < 3; ++a) {
        const float* X = Xp[a];
        __syncthreads();
#pragma unroll
        for (int i = 0; i < KDIM / 16; ++i) {
            float4 v = *(const float4*)&X[(size_t)gn * KDIM + sk0 + 4 * i];
            Xs[(sk0 + 4 * i + 0) * 65 + sn] = v.x;
            Xs[(sk0 + 4 * i + 1) * 65 + sn] = v.y;
            Xs[(sk0 + 4 * i + 2) * 65 + sn] = v.z;
            Xs[(sk0 + 4 * i + 3) * 65 + sn] = v.w;
        }
        __syncthreads();
#pragma unroll 4
        for (int k = 0; k < KDIM; ++k) {
            float x0 = Xs[k * 65 + ln0];
            float x1 = Xs[k * 65 + ln1];
            const float4* wr = (const float4*)&Ws[(a * KDIM + k) * 64 + c0];
            float4 wA = wr[0];
            float4 wB = wr[1];
            a0[0] += x0 * wA.x; a0[1] += x0 * wA.y; a0[2] += x0 * wA.z; a0[3] += x0 * wA.w;
            a0[4] += x0 * wB.x; a0[5] += x0 * wB.y; a0[6] += x0 * wB.z; a0[7] += x0 * wB.w;
            a1[0] += x1 * wA.x; a1[1] += x1 * wA.y; a1[2] += x1 * wA.z; a1[3] += x1 * wA.w;
            a1[4] += x1 * wB.x; a1[5] += x1 * wB.y; a1[6] += x1 * wB.z; a1[7] += x1 * wB.w;
        }
    }

    float4 bA = *(const float4*)&b[c0];
    float4 bB = *(const float4*)&b[c0 + 4];
    int n0 = nbase + ln0, n1 = nbase + ln1;
    if (n0 < N) {
        float4 r0 = { fmaxf(a0[0] + bA.x, 0.f), fmaxf(a0[1] + bA.y, 0.f), fmaxf(a0[2] + bA.z, 0.f), fmaxf(a0[3] + bA.w, 0.f) };
        float4 r1 = { fmaxf(a0[4] + bB.x, 0.f), fmaxf(a0[5] + bB.y, 0.f), fmaxf(a0[6] + bB.z, 0.f), fmaxf(a0[7] + bB.w, 0.f) };
        *(float4*)&out[(size_t)n0 * 64 + c0] = r0;
        *(float4*)&out[(size_t)n0 * 64 + c0 + 4] = r1;
    }
    if (n1 < N) {
        float4 r0 = { fmaxf(a1[0] + bA.x, 0.f), fmaxf(a1[1] + bA.y, 0.f), fmaxf(a1[2] + bA.z, 0.f), fmaxf(a1[3] + bA.w, 0.f) };
        float4 r1 = { fmaxf(a1[4] + bB.x, 0.f), fmaxf(a1[5] + bB.y, 0.f), fmaxf(a1[6] + bB.z, 0.f), fmaxf(a1[7] + bB.w, 0.f) };
        *(float4*)&out[(size_t)n1 * 64 + c0] = r0;
        *(float4*)&out[(size_t)n1 * 64 + c0 + 4] = r1;
    }
}

// ---------------- EdgeConv stage 1 as tiled GEMM: [m|p] = X @ [Wt | Wt+Wp] ----------------

__global__ __launch_bounds__(256) void k_e1_t(const float* __restrict__ X, const float* __restrict__ Wt,
                                              const float* __restrict__ Wp, const float* __restrict__ bt,
                                              const float* __restrict__ bp, float* __restrict__ m,
                                              float* __restrict__ pbuf, int N) {
    __shared__ float Wl[64 * 128];
    __shared__ float Xs[64 * 65];
    int t = threadIdx.x;
    for (int idx = t; idx < 64 * 64; idx += 256) {
        int k = idx >> 6, c = idx & 63;
        float wt = Wt[idx];
        Wl[k * 128 + c] = wt;
        Wl[k * 128 + 64 + c] = wt + Wp[idx];
    }

    int nbase = blockIdx.x * 64;
    int ln0 = t & 31, ln1 = 32 + ln0;
    int c0 = (t >> 5) * 16;

    int sn = t & 63;
    int sk0 = (t >> 6) * 16;
    int gn = nbase + sn; if (gn >= N) gn = N - 1;
#pragma unroll
    for (int i = 0; i < 4; ++i) {
        float4 v = *(const float4*)&X[(size_t)gn * 64 + sk0 + 4 * i];
        Xs[(sk0 + 4 * i + 0) * 65 + sn] = v.x;
        Xs[(sk0 + 4 * i + 1) * 65 + sn] = v.y;
        Xs[(sk0 + 4 * i + 2) * 65 + sn] = v.z;
        Xs[(sk0 + 4 * i + 3) * 65 + sn] = v.w;
    }
    __syncthreads();

    float a0[16], a1[16];
#pragma unroll
    for (int i = 0; i < 16; ++i) { a0[i] = 0.f; a1[i] = 0.f; }

#pragma unroll 2
    for (int k = 0; k < 64; ++k) {
        float x0 = Xs[k * 65 + ln0];
        float x1 = Xs[k * 65 + ln1];
        const float4* wr = (const float4*)&Wl[k * 128 + c0];
#pragma unroll
        for (int q = 0; q < 4; ++q) {
            float4 w = wr[q];
            a0[4 * q + 0] += x0 * w.x; a0[4 * q + 1] += x0 * w.y; a0[4 * q + 2] += x0 * w.z; a0[4 * q + 3] += x0 * w.w;
            a1[4 * q + 0] += x1 * w.x; a1[4 * q + 1] += x1 * w.y; a1[4 * q + 2] += x1 * w.z; a1[4 * q + 3] += x1 * w.w;
        }
    }

    int n0 = nbase + ln0, n1 = nbase + ln1;
    if (c0 < 64) {
        if (n0 < N) {
#pragma unroll
            for (int q = 0; q < 4; ++q) {
                float4 r = { a0[4 * q], a0[4 * q + 1], a0[4 * q + 2], a0[4 * q + 3] };
                *(float4*)&m[(size_t)n0 * 64 + c0 + 4 * q] = r;
            }
        }
        if (n1 < N) {
#pragma unroll
            for (int q = 0; q < 4; ++q) {
                float4 r = { a1[4 * q], a1[4 * q + 1], a1[4 * q + 2], a1[4 * q + 3] };
                *(float4*)&m[(size_t)n1 * 64 + c0 + 4 * q] = r;
            }
        }
    } else {
        int cc = c0 - 64;
        float bb[16];
#pragma unroll
        for (int i = 0; i < 16; ++i) bb[i] = bt[cc + i] + bp[cc + i];
        if (n0 < N) {
#pragma unroll
            for (int q = 0; q < 4; ++q) {
                float4 r = { a0[4 * q] + bb[4 * q], a0[4 * q + 1] + bb[4 * q + 1], a0[4 * q + 2] + bb[4 * q + 2], a0[4 * q + 3] + bb[4 * q + 3] };
                *(float4*)&pbuf[(size_t)n0 * 64 + cc + 4 * q] = r;
            }
        }
        if (n1 < N) {
#pragma unroll
            for (int q = 0; q < 4; ++q) {
                float4 r = { a1[4 * q] + bb[4 * q], a1[4 * q + 1] + bb[4 * q + 1], a1[4 * q + 2] + bb[4 * q + 2], a1[4 * q + 3] + bb[4 * q + 3] };
                *(float4*)&pbuf[(size_t)n1 * 64 + cc + 4 * q] = r;
            }
        }
    }
}

// ---------------- EdgeConv stage 2: out = relu(p[n] + max_j(-m[src_j])), 0 if no in-edges ----------------

__global__ __launch_bounds__(256) void k_e2(const float* __restrict__ m, const float* __restrict__ pbuf,
                                            const int* __restrict__ row_off, const int* __restrict__ csr,
                                            float* __restrict__ out, int N) {
    int t = blockIdx.x * blockDim.x + threadIdx.x;
    int node = t >> 6;
    int d = t & 63;
    if (node >= N) return;
    int beg = row_off[node], end = row_off[node + 1];
    float a0 = -INFINITY, a1 = -INFINITY, a2 = -INFINITY, a3 = -INFINITY;
    int j = beg;
    for (; j + 3 < end; j += 4) {
        int s0 = csr[j], s1 = csr[j + 1], s2 = csr[j + 2], s3 = csr[j + 3];
        a0 = fmaxf(a0, -m[s0 * 64 + d]);
        a1 = fmaxf(a1, -m[s1 * 64 + d]);
        a2 = fmaxf(a2, -m[s2 * 64 + d]);
        a3 = fmaxf(a3, -m[s3 * 64 + d]);
    }
    for (; j < end; ++j) {
        int s = csr[j];
        a0 = fmaxf(a0, -m[s * 64 + d]);
    }
    float r = 0.f;
    if (end > beg) r = fmaxf(pbuf[node * 64 + d] + fmaxf(fmaxf(a0, a1), fmaxf(a2, a3)), 0.f);
    out[node * 64 + d] = r;
}

// ---------------- graph mean pooling (segmented: gid is sorted) ----------------

__global__ __launch_bounds__(256) void k_pool(const float* __restrict__ h, const int* __restrict__ gid,
                                              float* __restrict__ out, float* __restrict__ gcnt, int N) {
    const int CHUNK = 128;
    int wave = blockIdx.x * 4 + (threadIdx.x >> 6);
    int lane = threadIdx.x & 63;
    int beg = wave * CHUNK;
    if (beg >= N) return;
    int end = beg + CHUNK < N ? beg + CHUNK : N;
    int gcur = gid[beg];
    float acc = 0.f;
    int cnt = 0;
    for (int n = beg; n < end; ++n) {
        int g = gid[n];
        float v = h[n * 64 + lane];
        if (g != gcur) {
            atomicAdd(&out[gcur * 64 + lane], acc);
            if (lane == 0) atomicAdd(&gcnt[gcur], (float)cnt);
            gcur = g; acc = 0.f; cnt = 0;
        }
        acc += v;
        ++cnt;
    }
    atomicAdd(&out[gcur * 64 + lane], acc);
    if (lane == 0) atomicAdd(&gcnt[gcur], (float)cnt);
}

__global__ __launch_bounds__(256) void k_div(float* __restrict__ out, const float* __restrict__ gcnt, int total) {
    int i = blockIdx.x * blockDim.x + threadIdx.x;
    if (i < total) out[i] /= fmaxf(gcnt[i >> 6], 1.f);
}

// ---------------- launcher ----------------

extern "C" void kernel_launch(void* const* d_in, const int* in_sizes, int n_in,
                              void* d_out, int out_size, void* d_ws, size_t ws_size,
                              hipStream_t stream) {
    const float* feat = (const float*)d_in[0];
    const int* src = (const int*)d_in[1];
    const int* dst = (const int*)d_in[2];
    const int* gid = (const int*)d_in[3];
    const float* W1 = (const float*)d_in[4];  const float* b1 = (const float*)d_in[5];
    const float* W2 = (const float*)d_in[6];  const float* b2 = (const float*)d_in[7];
    const float* W3 = (const float*)d_in[8];  const float* b3 = (const float*)d_in[9];
    const float* Wt1 = (const float*)d_in[10]; const float* bt1 = (const float*)d_in[11];
    const float* Wp1 = (const float*)d_in[12]; const float* bp1 = (const float*)d_in[13];
    const float* Wt2 = (const float*)d_in[14]; const float* bt2 = (const float*)d_in[15];
    const float* Wp2 = (const float*)d_in[16]; const float* bp2 = (const float*)d_in[17];
    float* out = (float*)d_out;

    const int N = in_sizes[0] / 16;
    const int E = in_sizes[1];
    const int G = out_size / 64;
    const int nb = (N + 255) >> 8;      // buckets (must be <= 512)

    char* p = (char*)d_ws;
    auto alloc = [&](size_t nbytes) {
        void* r = (void*)p;
        p += (nbytes + 255) & ~(size_t)255;
        return r;
    };
    int* cnt      = (int*)alloc((size_t)N * 4);
    int* row_off  = (int*)alloc((size_t)(N + 1) * 4);
    int* csr      = (int*)alloc((size_t)E * 4);
    int* bsum     = (int*)alloc(512 * 4);
    int* bcnt     = (int*)alloc(512 * 4);
    int* boff     = (int*)alloc(513 * 4);
    int* bcur     = (int*)alloc(512 * 4);
    float* dinv   = (float*)alloc((size_t)N * 4);
    float* bufA   = (float*)alloc((size_t)N * 64 * 4);
    float* bufB   = (float*)alloc((size_t)N * 64 * 4);
    float* bufC   = (float*)alloc((size_t)N * 64 * 4);
    float* bufD   = (float*)alloc((size_t)N * 64 * 4);
    float* gcnt   = (float*)alloc((size_t)G * 4);
    uint2* ebuf   = (uint2*)bufA;       // alias: bufA unused until after CSR build (needs E*8 <= N*256)

    hipMemsetAsync(bcnt, 0, 512 * 4, stream);
    hipMemsetAsync(gcnt, 0, (size_t)G * 4, stream);
    hipMemsetAsync(d_out, 0, (size_t)out_size * 4, stream);

    const int B = (N + 255) / 256;
    const int ebk = (E + 255) / 256;
    const int nb64 = (N * 64 + 255) / 256;
    const int nb16 = (N * 16 + 255) / 256;
    const int npool = ((N + 127) / 128 + 3) / 4;
    const int nbt = (N + 63) / 64;

    // ---- bucketed CSR build
    k_bhist<<<256, 256, 0, stream>>>(dst, bcnt, E);
    k_scanBkt<<<1, 512, 0, stream>>>(bcnt, boff, bcur, nb, E);
    k_part<<<ebk, 256, 0, stream>>>(src, dst, bcur, ebuf, E);
    k_cnt<<<nb, 256, 0, stream>>>(ebuf, boff, cnt, N);
    k_scanA<<<B, 256, 0, stream>>>(cnt, bsum, N);
    k_scanB<<<1, 512, 0, stream>>>(bsum, B);
    k_scanC<<<B, 256, 0, stream>>>(cnt, bsum, row_off, dinv, N, E);
    k_scat2<<<nb, 256, 0, stream>>>(ebuf, boff, row_off, csr, N);

    // ---- Cheb layer 1 (IN=16) : X1 = -aggr(X0); X2 = -2*aggr(X1) - X0
    k_aggr<16><<<nb16, 256, 0, stream>>>(feat, nullptr, dinv, row_off, csr, bufA, -1.f, 0.f, N);
    k_aggr<16><<<nb16, 256, 0, stream>>>(bufA, feat, dinv, row_off, csr, bufB, -2.f, -1.f, N);
    k_cheb_t<16><<<nbt, 256, 0, stream>>>(feat, bufA, bufB, W1, b1, bufC, N);

    // ---- EdgeConv 1
    k_e1_t<<<nbt, 256, 0, stream>>>(bufC, Wt1, Wp1, bt1, bp1, bufA, bufB, N);
    k_e2<<<nb64, 256, 0, stream>>>(bufA, bufB, row_off, csr, bufD, N);

    // ---- Cheb layer 2
    k_aggr<64><<<nb64, 256, 0, stream>>>(bufD, nullptr, dinv, row_off, csr, bufA, -1.f, 0.f, N);
    k_aggr<64><<<nb64, 256, 0, stream>>>(bufA, bufD, dinv, row_off, csr, bufB, -2.f, -1.f, N);
    k_cheb_t<64><<<nbt, 256, 0, stream>>>(bufD, bufA, bufB, W2, b2, bufC, N);

    // ---- EdgeConv 2
    k_e1_t<<<nbt, 256, 0, stream>>>(bufC, Wt2, Wp2, bt2, bp2, bufA, bufB, N);
    k_e2<<<nb64, 256, 0, stream>>>(bufA, bufB, row_off, csr, bufD, N);

    // ---- Cheb layer 3
    k_aggr<64><<<nb64, 256, 0, stream>>>(bufD, nullptr, dinv, row_off, csr, bufA, -1.f, 0.f, N);
    k_aggr<64><<<nb64, 256, 0, stream>>>(bufA, bufD, dinv, row_off, csr, bufB, -2.f, -1.f, N);
    k_cheb_t<64><<<nbt, 256, 0, stream>>>(bufD, bufA, bufB, W3, b3, bufC, N);

    // ---- per-graph mean pooling
    k_pool<<<npool, 256, 0, stream>>>(bufC, gid, out, gcnt, N);
    k_div<<<(out_size + 255) / 256, 256, 0, stream>>>(out, gcnt, out_size);
}

// Round 8
// 1013.012 us; speedup vs baseline: 1.4272x; 1.4272x over previous
//
#include <hip/hip_runtime.h>
#include <hip/hip_bf16.h>
#include <math.h>

__device__ __forceinline__ unsigned short bfb(float x) {
    union { __hip_bfloat16 h; unsigned short u; } c;
    c.h = __float2bfloat16(x);
    return c.u;
}
__device__ __forceinline__ float bf2f(__hip_bfloat16 h) { return __bfloat162float(h); }

// ---------------- CSR build (R6-verified: 100k cursors -> low atomic contention) ----------------

__global__ __launch_bounds__(256) void k_hist(const int* __restrict__ dst, int* __restrict__ cnt, int E) {
    int i = blockIdx.x * blockDim.x + threadIdx.x;
    if (i < E) atomicAdd(&cnt[dst[i]], 1);
}

__global__ __launch_bounds__(256) void k_scanA(const int* __restrict__ cnt, int* __restrict__ bsum, int N) {
    __shared__ int s[256];
    int t = threadIdx.x;
    int i = blockIdx.x * 256 + t;
    s[t] = (i < N) ? cnt[i] : 0;
    __syncthreads();
    for (int off = 128; off > 0; off >>= 1) {
        if (t < off) s[t] += s[t + off];
        __syncthreads();
    }
    if (t == 0) bsum[blockIdx.x] = s[0];
}

__global__ __launch_bounds__(512) void k_scanB(int* __restrict__ bsum, int B) {
    __shared__ int s[512];
    int t = threadIdx.x;
    int v = (t < B) ? bsum[t] : 0;
    s[t] = v;
    __syncthreads();
    for (int off = 1; off < 512; off <<= 1) {
        int x = (t >= off) ? s[t - off] : 0;
        __syncthreads();
        s[t] += x;
        __syncthreads();
    }
    if (t < B) bsum[t] = s[t] - v;   // exclusive
}

__global__ __launch_bounds__(256) void k_scanC(const int* __restrict__ cnt, const int* __restrict__ bsum,
                                               int* __restrict__ row_off, int* __restrict__ cursor,
                                               float* __restrict__ dinv, int N, int E) {
    __shared__ int s[256];
    int t = threadIdx.x;
    int i = blockIdx.x * 256 + t;
    int v = (i < N) ? cnt[i] : 0;
    s[t] = v;
    __syncthreads();
    for (int off = 1; off < 256; off <<= 1) {
        int x = (t >= off) ? s[t - off] : 0;
        __syncthreads();
        s[t] += x;
        __syncthreads();
    }
    if (i < N) {
        int excl = bsum[blockIdx.x] + s[t] - v;
        row_off[i] = excl;
        cursor[i]  = excl;
        dinv[i]    = rsqrtf((float)(v > 1 ? v : 1));
    }
    if (i == 0) row_off[N] = E;
}

__global__ __launch_bounds__(256) void k_scatter(const int* __restrict__ src, const int* __restrict__ dst,
                                                 int* __restrict__ cursor, int* __restrict__ csr, int E) {
    int i = blockIdx.x * blockDim.x + threadIdx.x;
    if (i < E) {
        int d = dst[i];
        int pos = atomicAdd(&cursor[d], 1);
        csr[pos] = src[i];
    }
}

// ---------------- feat -> bf16 pre-scaled (featd = feat * dinv) ----------------

__global__ __launch_bounds__(256) void k_feat16(const float* __restrict__ feat, const float* __restrict__ dinv,
                                                __hip_bfloat16* __restrict__ featd, int total) {
    int i = blockIdx.x * 256 + threadIdx.x;
    if (i < total) featd[i] = __float2bfloat16(feat[i] * dinv[i >> 4]);
}

// ---------------- Chebyshev aggregation (bf16 gather, fp32 accumulate) ----------------
// Xd is pre-scaled by dinv[s]. out = alpha*dinv[n]*sum + beta*Z. outd (optional) = out*dinv[n] in bf16.

template <int D>
__global__ __launch_bounds__(256) void k_aggr_b(const __hip_bfloat16* __restrict__ Xd, const float* __restrict__ Z,
                                                const float* __restrict__ dinv,
                                                const int* __restrict__ row_off, const int* __restrict__ csr,
                                                float* __restrict__ out, __hip_bfloat16* __restrict__ outd,
                                                float alpha, float beta, int N) {
    int t = blockIdx.x * blockDim.x + threadIdx.x;
    int node = t / D;
    int d = t % D;
    if (node >= N) return;
    int beg = row_off[node], end = row_off[node + 1];
    float a0 = 0.f, a1 = 0.f, a2 = 0.f, a3 = 0.f;
    int j = beg;
    for (; j + 3 < end; j += 4) {
        int s0 = csr[j], s1 = csr[j + 1], s2 = csr[j + 2], s3 = csr[j + 3];
        a0 += bf2f(Xd[s0 * D + d]);
        a1 += bf2f(Xd[s1 * D + d]);
        a2 += bf2f(Xd[s2 * D + d]);
        a3 += bf2f(Xd[s3 * D + d]);
    }
    for (; j < end; ++j) a0 += bf2f(Xd[csr[j] * D + d]);
    float acc = (a0 + a1) + (a2 + a3);
    float dn = dinv[node];
    float v = alpha * dn * acc;
    if (Z) v += beta * Z[node * D + d];
    out[node * D + d] = v;
    if (outd) outd[node * D + d] = __float2bfloat16(v * dn);
}

// ---------------- Cheb matmul, LDS-tiled GEMM (unroll capped: R5 full-unroll spilled) ----------------

template <int KDIM>
__global__ __launch_bounds__(256) void k_cheb_t(const float* __restrict__ X0, const float* __restrict__ X1,
                                                const float* __restrict__ X2, const float* __restrict__ W,
                                                const float* __restrict__ b, float* __restrict__ out, int N) {
    __shared__ float Ws[3 * KDIM * 64];
    __shared__ float Xs[KDIM * 65];
    int t = threadIdx.x;
    for (int idx = t; idx < 3 * KDIM * 64; idx += 256) Ws[idx] = W[idx];

    int nbase = blockIdx.x * 64;
    int ln0 = t & 31;
    int ln1 = 32 + ln0;
    int c0  = (t >> 5) * 8;

    int sn  = t & 63;
    int sk0 = (t >> 6) * (KDIM / 4);
    int gn  = nbase + sn; if (gn >= N) gn = N - 1;

    float a0[8], a1[8];
#pragma unroll
    for (int i = 0; i < 8; ++i) { a0[i] = 0.f; a1[i] = 0.f; }

    const float* Xp[3] = { X0, X1, X2 };
#pragma unroll 1
    for (int a = 0; a < 3; ++a) {
        const float* X = Xp[a];
        __syncthreads();
#pragma unroll
        for (int i = 0; i < KDIM / 16; ++i) {
            float4 v = *(const float4*)&X[(size_t)gn * KDIM + sk0 + 4 * i];
            Xs[(sk0 + 4 * i + 0) * 65 + sn] = v.x;
            Xs[(sk0 + 4 * i + 1) * 65 + sn] = v.y;
            Xs[(sk0 + 4 * i + 2) * 65 + sn] = v.z;
            Xs[(sk0 + 4 * i + 3) * 65 + sn] = v.w;
        }
        __syncthreads();
#pragma unroll 4
        for (int k = 0; k < KDIM; ++k) {
            float x0 = Xs[k * 65 + ln0];
            float x1 = Xs[k * 65 + ln1];
            const float4* wr = (const float4*)&Ws[(a * KDIM + k) * 64 + c0];
            float4 wA = wr[0];
            float4 wB = wr[1];
            a0[0] += x0 * wA.x; a0[1] += x0 * wA.y; a0[2] += x0 * wA.z; a0[3] += x0 * wA.w;
            a0[4] += x0 * wB.x; a0[5] += x0 * wB.y; a0[6] += x0 * wB.z; a0[7] += x0 * wB.w;
            a1[0] += x1 * wA.x; a1[1] += x1 * wA.y; a1[2] += x1 * wA.z; a1[3] += x1 * wA.w;
            a1[4] += x1 * wB.x; a1[5] += x1 * wB.y; a1[6] += x1 * wB.z; a1[7] += x1 * wB.w;
        }
    }

    float4 bA = *(const float4*)&b[c0];
    float4 bB = *(const float4*)&b[c0 + 4];
    int n0 = nbase + ln0, n1 = nbase + ln1;
    if (n0 < N) {
        float4 r0 = { fmaxf(a0[0] + bA.x, 0.f), fmaxf(a0[1] + bA.y, 0.f), fmaxf(a0[2] + bA.z, 0.f), fmaxf(a0[3] + bA.w, 0.f) };
        float4 r1 = { fmaxf(a0[4] + bB.x, 0.f), fmaxf(a0[5] + bB.y, 0.f), fmaxf(a0[6] + bB.z, 0.f), fmaxf(a0[7] + bB.w, 0.f) };
        *(float4*)&out[(size_t)n0 * 64 + c0] = r0;
        *(float4*)&out[(size_t)n0 * 64 + c0 + 4] = r1;
    }
    if (n1 < N) {
        float4 r0 = { fmaxf(a1[0] + bA.x, 0.f), fmaxf(a1[1] + bA.y, 0.f), fmaxf(a1[2] + bA.z, 0.f), fmaxf(a1[3] + bA.w, 0.f) };
        float4 r1 = { fmaxf(a1[4] + bB.x, 0.f), fmaxf(a1[5] + bB.y, 0.f), fmaxf(a1[6] + bB.z, 0.f), fmaxf(a1[7] + bB.w, 0.f) };
        *(float4*)&out[(size_t)n1 * 64 + c0] = r0;
        *(float4*)&out[(size_t)n1 * 64 + c0 + 4] = r1;
    }
}

// ---------------- EdgeConv stage 1 as tiled GEMM: [m|p] = X @ [Wt | Wt+Wp]; m also emitted as bf16 ----------------

__global__ __launch_bounds__(256) void k_e1_t(const float* __restrict__ X, const float* __restrict__ Wt,
                                              const float* __restrict__ Wp, const float* __restrict__ bt,
                                              const float* __restrict__ bp, float* __restrict__ m,
                                              __hip_bfloat16* __restrict__ md, float* __restrict__ pbuf, int N) {
    __shared__ float Wl[64 * 128];
    __shared__ float Xs[64 * 65];
    int t = threadIdx.x;
    for (int idx = t; idx < 64 * 64; idx += 256) {
        int k = idx >> 6, c = idx & 63;
        float wt = Wt[idx];
        Wl[k * 128 + c] = wt;
        Wl[k * 128 + 64 + c] = wt + Wp[idx];
    }

    int nbase = blockIdx.x * 64;
    int ln0 = t & 31, ln1 = 32 + ln0;
    int c0 = (t >> 5) * 16;

    int sn = t & 63;
    int sk0 = (t >> 6) * 16;
    int gn = nbase + sn; if (gn >= N) gn = N - 1;
#pragma unroll
    for (int i = 0; i < 4; ++i) {
        float4 v = *(const float4*)&X[(size_t)gn * 64 + sk0 + 4 * i];
        Xs[(sk0 + 4 * i + 0) * 65 + sn] = v.x;
        Xs[(sk0 + 4 * i + 1) * 65 + sn] = v.y;
        Xs[(sk0 + 4 * i + 2) * 65 + sn] = v.z;
        Xs[(sk0 + 4 * i + 3) * 65 + sn] = v.w;
    }
    __syncthreads();

    float a0[16], a1[16];
#pragma unroll
    for (int i = 0; i < 16; ++i) { a0[i] = 0.f; a1[i] = 0.f; }

#pragma unroll 2
    for (int k = 0; k < 64; ++k) {
        float x0 = Xs[k * 65 + ln0];
        float x1 = Xs[k * 65 + ln1];
        const float4* wr = (const float4*)&Wl[k * 128 + c0];
#pragma unroll
        for (int q = 0; q < 4; ++q) {
            float4 w = wr[q];
            a0[4 * q + 0] += x0 * w.x; a0[4 * q + 1] += x0 * w.y; a0[4 * q + 2] += x0 * w.z; a0[4 * q + 3] += x0 * w.w;
            a1[4 * q + 0] += x1 * w.x; a1[4 * q + 1] += x1 * w.y; a1[4 * q + 2] += x1 * w.z; a1[4 * q + 3] += x1 * w.w;
        }
    }

    int n0 = nbase + ln0, n1 = nbase + ln1;
    unsigned short* mdu = (unsigned short*)md;
    if (c0 < 64) {               // band -> m (fp32 + bf16 copy)
        if (n0 < N) {
#pragma unroll
            for (int q = 0; q < 4; ++q) {
                float4 r = { a0[4 * q], a0[4 * q + 1], a0[4 * q + 2], a0[4 * q + 3] };
                *(float4*)&m[(size_t)n0 * 64 + c0 + 4 * q] = r;
                ushort4 u = { bfb(r.x), bfb(r.y), bfb(r.z), bfb(r.w) };
                *(ushort4*)&mdu[(size_t)n0 * 64 + c0 + 4 * q] = u;
            }
        }
        if (n1 < N) {
#pragma unroll
            for (int q = 0; q < 4; ++q) {
                float4 r = { a1[4 * q], a1[4 * q + 1], a1[4 * q + 2], a1[4 * q + 3] };
                *(float4*)&m[(size_t)n1 * 64 + c0 + 4 * q] = r;
                ushort4 u = { bfb(r.x), bfb(r.y), bfb(r.z), bfb(r.w) };
                *(ushort4*)&mdu[(size_t)n1 * 64 + c0 + 4 * q] = u;
            }
        }
    } else {                     // band -> pbuf (+ bias)
        int cc = c0 - 64;
        float bb[16];
#pragma unroll
        for (int i = 0; i < 16; ++i) bb[i] = bt[cc + i] + bp[cc + i];
        if (n0 < N) {
#pragma unroll
            for (int q = 0; q < 4; ++q) {
                float4 r = { a0[4 * q] + bb[4 * q], a0[4 * q + 1] + bb[4 * q + 1], a0[4 * q + 2] + bb[4 * q + 2], a0[4 * q + 3] + bb[4 * q + 3] };
                *(float4*)&pbuf[(size_t)n0 * 64 + cc + 4 * q] = r;
            }
        }
        if (n1 < N) {
#pragma unroll
            for (int q = 0; q < 4; ++q) {
                float4 r = { a1[4 * q] + bb[4 * q], a1[4 * q + 1] + bb[4 * q + 1], a1[4 * q + 2] + bb[4 * q + 2], a1[4 * q + 3] + bb[4 * q + 3] };
                *(float4*)&pbuf[(size_t)n1 * 64 + cc + 4 * q] = r;
            }
        }
    }
}

// ---------------- EdgeConv stage 2 (bf16 gather): out = relu(p + max(-md[src])), + bf16*dinv copy ----------------

__global__ __launch_bounds__(256) void k_e2_b(const __hip_bfloat16* __restrict__ md, const float* __restrict__ pbuf,
                                              const int* __restrict__ row_off, const int* __restrict__ csr,
                                              const float* __restrict__ dinv, float* __restrict__ out,
                                              __hip_bfloat16* __restrict__ outd, int N) {
    int t = blockIdx.x * blockDim.x + threadIdx.x;
    int node = t >> 6;
    int d = t & 63;
    if (node >= N) return;
    int beg = row_off[node], end = row_off[node + 1];
    float a0 = -INFINITY, a1 = -INFINITY, a2 = -INFINITY, a3 = -INFINITY;
    int j = beg;
    for (; j + 3 < end; j += 4) {
        int s0 = csr[j], s1 = csr[j + 1], s2 = csr[j + 2], s3 = csr[j + 3];
        a0 = fmaxf(a0, -bf2f(md[s0 * 64 + d]));
        a1 = fmaxf(a1, -bf2f(md[s1 * 64 + d]));
        a2 = fmaxf(a2, -bf2f(md[s2 * 64 + d]));
        a3 = fmaxf(a3, -bf2f(md[s3 * 64 + d]));
    }
    for (; j < end; ++j) a0 = fmaxf(a0, -bf2f(md[csr[j] * 64 + d]));
    float r = 0.f;
    if (end > beg) r = fmaxf(pbuf[node * 64 + d] + fmaxf(fmaxf(a0, a1), fmaxf(a2, a3)), 0.f);
    out[node * 64 + d] = r;
    outd[node * 64 + d] = __float2bfloat16(r * dinv[node]);
}

// ---------------- graph mean pooling (segmented: gid is sorted) ----------------

__global__ __launch_bounds__(256) void k_pool(const float* __restrict__ h, const int* __restrict__ gid,
                                              float* __restrict__ out, float* __restrict__ gcnt, int N) {
    const int CHUNK = 128;
    int wave = blockIdx.x * 4 + (threadIdx.x >> 6);
    int lane = threadIdx.x & 63;
    int beg = wave * CHUNK;
    if (beg >= N) return;
    int end = beg + CHUNK < N ? beg + CHUNK : N;
    int gcur = gid[beg];
    float acc = 0.f;
    int cnt = 0;
    for (int n = beg; n < end; ++n) {
        int g = gid[n];
        float v = h[n * 64 + lane];
        if (g != gcur) {
            atomicAdd(&out[gcur * 64 + lane], acc);
            if (lane == 0) atomicAdd(&gcnt[gcur], (float)cnt);
            gcur = g; acc = 0.f; cnt = 0;
        }
        acc += v;
        ++cnt;
    }
    atomicAdd(&out[gcur * 64 + lane], acc);
    if (lane == 0) atomicAdd(&gcnt[gcur], (float)cnt);
}

__global__ __launch_bounds__(256) void k_div(float* __restrict__ out, const float* __restrict__ gcnt, int total) {
    int i = blockIdx.x * blockDim.x + threadIdx.x;
    if (i < total) out[i] /= fmaxf(gcnt[i >> 6], 1.f);
}

// ---------------- launcher ----------------

extern "C" void kernel_launch(void* const* d_in, const int* in_sizes, int n_in,
                              void* d_out, int out_size, void* d_ws, size_t ws_size,
                              hipStream_t stream) {
    const float* feat = (const float*)d_in[0];
    const int* src = (const int*)d_in[1];
    const int* dst = (const int*)d_in[2];
    const int* gid = (const int*)d_in[3];
    const float* W1 = (const float*)d_in[4];  const float* b1 = (const float*)d_in[5];
    const float* W2 = (const float*)d_in[6];  const float* b2 = (const float*)d_in[7];
    const float* W3 = (const float*)d_in[8];  const float* b3 = (const float*)d_in[9];
    const float* Wt1 = (const float*)d_in[10]; const float* bt1 = (const float*)d_in[11];
    const float* Wp1 = (const float*)d_in[12]; const float* bp1 = (const float*)d_in[13];
    const float* Wt2 = (const float*)d_in[14]; const float* bt2 = (const float*)d_in[15];
    const float* Wp2 = (const float*)d_in[16]; const float* bp2 = (const float*)d_in[17];
    float* out = (float*)d_out;

    const int N = in_sizes[0] / 16;
    const int E = in_sizes[1];
    const int G = out_size / 64;

    char* p = (char*)d_ws;
    auto alloc = [&](size_t nbytes) {
        void* r = (void*)p;
        p += (nbytes + 255) & ~(size_t)255;
        return r;
    };
    int* cnt      = (int*)alloc((size_t)N * 4);
    int* row_off  = (int*)alloc((size_t)(N + 1) * 4);
    int* cursor   = (int*)alloc((size_t)N * 4);
    int* csr      = (int*)alloc((size_t)E * 4);
    int* bsum     = (int*)alloc(512 * 4);
    float* dinv   = (float*)alloc((size_t)N * 4);
    float* bufA   = (float*)alloc((size_t)N * 64 * 4);
    float* bufB   = (float*)alloc((size_t)N * 64 * 4);
    float* bufC   = (float*)alloc((size_t)N * 64 * 4);
    float* bufD   = (float*)alloc((size_t)N * 64 * 4);
    __hip_bfloat16* md = (__hip_bfloat16*)alloc((size_t)N * 64 * 2);
    float* gcnt   = (float*)alloc((size_t)G * 4);

    // bf16 scratch carved from bufC's DEAD windows:
    //  hd (=out*dinv of e2 / featd at layer1) = bufC bytes [0, N*128)
    //  xd (=X1*dinv between aggr#1 and aggr#2) = bufC bytes [N*128, N*256)
    //  both dead when k_cheb_t writes bufC; bufC dead (consumed by e1) when e2 writes hd.
    __hip_bfloat16* hd = (__hip_bfloat16*)bufC;
    __hip_bfloat16* xd = (__hip_bfloat16*)bufC + (size_t)N * 64;

    hipMemsetAsync(cnt, 0, (size_t)N * 4, stream);
    hipMemsetAsync(gcnt, 0, (size_t)G * 4, stream);
    hipMemsetAsync(d_out, 0, (size_t)out_size * 4, stream);

    const int B = (N + 255) / 256;
    const int ebk = (E + 255) / 256;
    const int nb64 = (N * 64 + 255) / 256;
    const int nb16 = (N * 16 + 255) / 256;
    const int npool = ((N + 127) / 128 + 3) / 4;
    const int nbt = (N + 63) / 64;

    k_hist<<<ebk, 256, 0, stream>>>(dst, cnt, E);
    k_scanA<<<B, 256, 0, stream>>>(cnt, bsum, N);
    k_scanB<<<1, 512, 0, stream>>>(bsum, B);
    k_scanC<<<B, 256, 0, stream>>>(cnt, bsum, row_off, cursor, dinv, N, E);
    k_scatter<<<ebk, 256, 0, stream>>>(src, dst, cursor, csr, E);

    // ---- Cheb layer 1 (IN=16): featd = feat*dinv (bf16, in hd slot)
    k_feat16<<<nb16, 256, 0, stream>>>(feat, dinv, hd, N * 16);
    k_aggr_b<16><<<nb16, 256, 0, stream>>>(hd, nullptr, dinv, row_off, csr, bufA, xd, -1.f, 0.f, N);
    k_aggr_b<16><<<nb16, 256, 0, stream>>>(xd, feat, dinv, row_off, csr, bufB, nullptr, -2.f, -1.f, N);
    k_cheb_t<16><<<nbt, 256, 0, stream>>>(feat, bufA, bufB, W1, b1, bufC, N);

    // ---- EdgeConv 1
    k_e1_t<<<nbt, 256, 0, stream>>>(bufC, Wt1, Wp1, bt1, bp1, bufA, md, bufB, N);
    k_e2_b<<<nb64, 256, 0, stream>>>(md, bufB, row_off, csr, dinv, bufD, hd, N);

    // ---- Cheb layer 2
    k_aggr_b<64><<<nb64, 256, 0, stream>>>(hd, nullptr, dinv, row_off, csr, bufA, xd, -1.f, 0.f, N);
    k_aggr_b<64><<<nb64, 256, 0, stream>>>(xd, bufD, dinv, row_off, csr, bufB, nullptr, -2.f, -1.f, N);
    k_cheb_t<64><<<nbt, 256, 0, stream>>>(bufD, bufA, bufB, W2, b2, bufC, N);

    // ---- EdgeConv 2
    k_e1_t<<<nbt, 256, 0, stream>>>(bufC, Wt2, Wp2, bt2, bp2, bufA, md, bufB, N);
    k_e2_b<<<nb64, 256, 0, stream>>>(md, bufB, row_off, csr, dinv, bufD, hd, N);

    // ---- Cheb layer 3
    k_aggr_b<64><<<nb64, 256, 0, stream>>>(hd, nullptr, dinv, row_off, csr, bufA, xd, -1.f, 0.f, N);
    k_aggr_b<64><<<nb64, 256, 0, stream>>>(xd, bufD, dinv, row_off, csr, bufB, nullptr, -2.f, -1.f, N);
    k_cheb_t<64><<<nbt, 256, 0, stream>>>(bufD, bufA, bufB, W3, b3, bufC, N);

    // ---- per-graph mean pooling
    k_pool<<<npool, 256, 0, stream>>>(bufC, gid, out, gcnt, N);
    k_div<<<(out_size + 255) / 256, 256, 0, stream>>>(out, gcnt, out_size);
}

// Round 9
// 954.197 us; speedup vs baseline: 1.5151x; 1.0616x over previous
//
#include <hip/hip_runtime.h>
#include <hip/hip_bf16.h>
#include <math.h>

__device__ __forceinline__ unsigned short bfb(float x) {
    union { __hip_bfloat16 h; unsigned short u; } c;
    c.h = __float2bfloat16(x);
    return c.u;
}
__device__ __forceinline__ float bf2f(unsigned short u) {
    union { unsigned int i; float f; } c;
    c.i = ((unsigned int)u) << 16;
    return c.f;
}

// ---------------- CSR build (R6-verified: 100k cursors -> low atomic contention) ----------------

__global__ __launch_bounds__(256) void k_hist(const int* __restrict__ dst, int* __restrict__ cnt, int E) {
    int i = blockIdx.x * blockDim.x + threadIdx.x;
    if (i < E) atomicAdd(&cnt[dst[i]], 1);
}

__global__ __launch_bounds__(256) void k_scanA(const int* __restrict__ cnt, int* __restrict__ bsum, int N) {
    __shared__ int s[256];
    int t = threadIdx.x;
    int i = blockIdx.x * 256 + t;
    s[t] = (i < N) ? cnt[i] : 0;
    __syncthreads();
    for (int off = 128; off > 0; off >>= 1) {
        if (t < off) s[t] += s[t + off];
        __syncthreads();
    }
    if (t == 0) bsum[blockIdx.x] = s[0];
}

__global__ __launch_bounds__(512) void k_scanB(int* __restrict__ bsum, int B) {
    __shared__ int s[512];
    int t = threadIdx.x;
    int v = (t < B) ? bsum[t] : 0;
    s[t] = v;
    __syncthreads();
    for (int off = 1; off < 512; off <<= 1) {
        int x = (t >= off) ? s[t - off] : 0;
        __syncthreads();
        s[t] += x;
        __syncthreads();
    }
    if (t < B) bsum[t] = s[t] - v;   // exclusive
}

__global__ __launch_bounds__(256) void k_scanC(const int* __restrict__ cnt, const int* __restrict__ bsum,
                                               int* __restrict__ row_off, int* __restrict__ cursor,
                                               float* __restrict__ dinv, int N, int E) {
    __shared__ int s[256];
    int t = threadIdx.x;
    int i = blockIdx.x * 256 + t;
    int v = (i < N) ? cnt[i] : 0;
    s[t] = v;
    __syncthreads();
    for (int off = 1; off < 256; off <<= 1) {
        int x = (t >= off) ? s[t - off] : 0;
        __syncthreads();
        s[t] += x;
        __syncthreads();
    }
    if (i < N) {
        int excl = bsum[blockIdx.x] + s[t] - v;
        row_off[i] = excl;
        cursor[i]  = excl;
        dinv[i]    = rsqrtf((float)(v > 1 ? v : 1));
    }
    if (i == 0) row_off[N] = E;
}

__global__ __launch_bounds__(256) void k_scatter(const int* __restrict__ src, const int* __restrict__ dst,
                                                 int* __restrict__ cursor, int* __restrict__ csr, int E) {
    int i = blockIdx.x * blockDim.x + threadIdx.x;
    if (i < E) {
        int d = dst[i];
        int pos = atomicAdd(&cursor[d], 1);
        csr[pos] = src[i];
    }
}

// ---------------- feat -> bf16 pre-scaled (featd = feat * dinv) ----------------

__global__ __launch_bounds__(256) void k_feat16(const float* __restrict__ feat, const float* __restrict__ dinv,
                                                unsigned short* __restrict__ featd, int total) {
    int i = blockIdx.x * 256 + threadIdx.x;
    if (i < total) featd[i] = bfb(feat[i] * dinv[i >> 4]);
}

// ---------------- 16-dim Chebyshev aggregation (bf16 gather, scalar layout) ----------------

__global__ __launch_bounds__(256) void k_aggr16(const unsigned short* __restrict__ Xd, const float* __restrict__ Z,
                                                const float* __restrict__ dinv,
                                                const int* __restrict__ row_off, const int* __restrict__ csr,
                                                float* __restrict__ out, unsigned short* __restrict__ outd,
                                                float alpha, float beta, int N) {
    const int D = 16;
    int t = blockIdx.x * blockDim.x + threadIdx.x;
    int node = t / D;
    int d = t % D;
    if (node >= N) return;
    int beg = row_off[node], end = row_off[node + 1];
    float a0 = 0.f, a1 = 0.f, a2 = 0.f, a3 = 0.f;
    int j = beg;
    for (; j + 3 < end; j += 4) {
        int s0 = csr[j], s1 = csr[j + 1], s2 = csr[j + 2], s3 = csr[j + 3];
        a0 += bf2f(Xd[s0 * D + d]);
        a1 += bf2f(Xd[s1 * D + d]);
        a2 += bf2f(Xd[s2 * D + d]);
        a3 += bf2f(Xd[s3 * D + d]);
    }
    for (; j < end; ++j) a0 += bf2f(Xd[csr[j] * D + d]);
    float acc = (a0 + a1) + (a2 + a3);
    float dn = dinv[node];
    float v = alpha * dn * acc;
    if (Z) v += beta * Z[node * D + d];
    out[node * D + d] = v;
    if (outd) outd[node * D + d] = bfb(v * dn);
}

// ---------------- 64-dim Chebyshev aggregation, PAIRED-EDGE gather ----------------
// Wave = node. Lanes 0-31 process even-offset edges, 32-63 odd: each lane loads
// ushort2 (dims 2c,2c+1) -> 2 edges per vmem issue, 4 in flight. Cross-half
// combine via shfl_xor(32); lanes 0-31 write float2 + bf16 copy.

__global__ __launch_bounds__(256) void k_aggr64(const unsigned short* __restrict__ Xd, const float* __restrict__ Z,
                                                const float* __restrict__ dinv,
                                                const int* __restrict__ row_off, const int* __restrict__ csr,
                                                float* __restrict__ out, unsigned short* __restrict__ outd,
                                                float alpha, float beta, int N) {
    int node = blockIdx.x * 4 + (threadIdx.x >> 6);
    if (node >= N) return;
    int lane = threadIdx.x & 63;
    int sub = lane >> 5;
    int c2 = (lane & 31) * 2;
    int beg = row_off[node], end = row_off[node + 1];
    float ax = 0.f, ay = 0.f, bx = 0.f, by = 0.f;
    int j = beg;
    for (; j + 3 < end; j += 4) {
        int sA = csr[j + sub];
        int sB = csr[j + 2 + sub];
        ushort2 xA = *(const ushort2*)&Xd[sA * 64 + c2];
        ushort2 xB = *(const ushort2*)&Xd[sB * 64 + c2];
        ax += bf2f(xA.x); ay += bf2f(xA.y);
        bx += bf2f(xB.x); by += bf2f(xB.y);
    }
    for (; j + 1 < end; j += 2) {
        int sA = csr[j + sub];
        ushort2 xA = *(const ushort2*)&Xd[sA * 64 + c2];
        ax += bf2f(xA.x); ay += bf2f(xA.y);
    }
    if (j < end && sub == 0) {
        int sA = csr[j];
        ushort2 xA = *(const ushort2*)&Xd[sA * 64 + c2];
        ax += bf2f(xA.x); ay += bf2f(xA.y);
    }
    float fx = ax + bx, fy = ay + by;
    fx += __shfl_xor(fx, 32);
    fy += __shfl_xor(fy, 32);
    if (sub == 0) {
        float dn = dinv[node];
        float vx = alpha * dn * fx;
        float vy = alpha * dn * fy;
        if (Z) {
            float2 zv = *(const float2*)&Z[(size_t)node * 64 + c2];
            vx += beta * zv.x;
            vy += beta * zv.y;
        }
        float2 r = { vx, vy };
        *(float2*)&out[(size_t)node * 64 + c2] = r;
        if (outd) {
            ushort2 u = { bfb(vx * dn), bfb(vy * dn) };
            *(ushort2*)&outd[(size_t)node * 64 + c2] = u;
        }
    }
}

// ---------------- Cheb matmul, LDS-tiled GEMM (unroll capped: R5 full-unroll spilled) ----------------

template <int KDIM>
__global__ __launch_bounds__(256) void k_cheb_t(const float* __restrict__ X0, const float* __restrict__ X1,
                                                const float* __restrict__ X2, const float* __restrict__ W,
                                                const float* __restrict__ b, float* __restrict__ out, int N) {
    __shared__ float Ws[3 * KDIM * 64];
    __shared__ float Xs[KDIM * 65];
    int t = threadIdx.x;
    for (int idx = t; idx < 3 * KDIM * 64; idx += 256) Ws[idx] = W[idx];

    int nbase = blockIdx.x * 64;
    int ln0 = t & 31;
    int ln1 = 32 + ln0;
    int c0  = (t >> 5) * 8;

    int sn  = t & 63;
    int sk0 = (t >> 6) * (KDIM / 4);
    int gn  = nbase + sn; if (gn >= N) gn = N - 1;

    float a0[8], a1[8];
#pragma unroll
    for (int i = 0; i < 8; ++i) { a0[i] = 0.f; a1[i] = 0.f; }

    const float* Xp[3] = { X0, X1, X2 };
#pragma unroll 1
    for (int a = 0; a < 3; ++a) {
        const float* X = Xp[a];
        __syncthreads();
#pragma unroll
        for (int i = 0; i < KDIM / 16; ++i) {
            float4 v = *(const float4*)&X[(size_t)gn * KDIM + sk0 + 4 * i];
            Xs[(sk0 + 4 * i + 0) * 65 + sn] = v.x;
            Xs[(sk0 + 4 * i + 1) * 65 + sn] = v.y;
            Xs[(sk0 + 4 * i + 2) * 65 + sn] = v.z;
            Xs[(sk0 + 4 * i + 3) * 65 + sn] = v.w;
        }
        __syncthreads();
#pragma unroll 4
        for (int k = 0; k < KDIM; ++k) {
            float x0 = Xs[k * 65 + ln0];
            float x1 = Xs[k * 65 + ln1];
            const float4* wr = (const float4*)&Ws[(a * KDIM + k) * 64 + c0];
            float4 wA = wr[0];
            float4 wB = wr[1];
            a0[0] += x0 * wA.x; a0[1] += x0 * wA.y; a0[2] += x0 * wA.z; a0[3] += x0 * wA.w;
            a0[4] += x0 * wB.x; a0[5] += x0 * wB.y; a0[6] += x0 * wB.z; a0[7] += x0 * wB.w;
            a1[0] += x1 * wA.x; a1[1] += x1 * wA.y; a1[2] += x1 * wA.z; a1[3] += x1 * wA.w;
            a1[4] += x1 * wB.x; a1[5] += x1 * wB.y; a1[6] += x1 * wB.z; a1[7] += x1 * wB.w;
        }
    }

    float4 bA = *(const float4*)&b[c0];
    float4 bB = *(const float4*)&b[c0 + 4];
    int n0 = nbase + ln0, n1 = nbase + ln1;
    if (n0 < N) {
        float4 r0 = { fmaxf(a0[0] + bA.x, 0.f), fmaxf(a0[1] + bA.y, 0.f), fmaxf(a0[2] + bA.z, 0.f), fmaxf(a0[3] + bA.w, 0.f) };
        float4 r1 = { fmaxf(a0[4] + bB.x, 0.f), fmaxf(a0[5] + bB.y, 0.f), fmaxf(a0[6] + bB.z, 0.f), fmaxf(a0[7] + bB.w, 0.f) };
        *(float4*)&out[(size_t)n0 * 64 + c0] = r0;
        *(float4*)&out[(size_t)n0 * 64 + c0 + 4] = r1;
    }
    if (n1 < N) {
        float4 r0 = { fmaxf(a1[0] + bA.x, 0.f), fmaxf(a1[1] + bA.y, 0.f), fmaxf(a1[2] + bA.z, 0.f), fmaxf(a1[3] + bA.w, 0.f) };
        float4 r1 = { fmaxf(a1[4] + bB.x, 0.f), fmaxf(a1[5] + bB.y, 0.f), fmaxf(a1[6] + bB.z, 0.f), fmaxf(a1[7] + bB.w, 0.f) };
        *(float4*)&out[(size_t)n1 * 64 + c0] = r0;
        *(float4*)&out[(size_t)n1 * 64 + c0 + 4] = r1;
    }
}

// ---------------- EdgeConv stage 1 as tiled GEMM: [m|p] = X @ [Wt | Wt+Wp]; m emitted as bf16 ----------------

__global__ __launch_bounds__(256) void k_e1_t(const float* __restrict__ X, const float* __restrict__ Wt,
                                              const float* __restrict__ Wp, const float* __restrict__ bt,
                                              const float* __restrict__ bp,
                                              unsigned short* __restrict__ md, float* __restrict__ pbuf, int N) {
    __shared__ float Wl[64 * 128];
    __shared__ float Xs[64 * 65];
    int t = threadIdx.x;
    for (int idx = t; idx < 64 * 64; idx += 256) {
        int k = idx >> 6, c = idx & 63;
        float wt = Wt[idx];
        Wl[k * 128 + c] = wt;
        Wl[k * 128 + 64 + c] = wt + Wp[idx];
    }

    int nbase = blockIdx.x * 64;
    int ln0 = t & 31, ln1 = 32 + ln0;
    int c0 = (t >> 5) * 16;

    int sn = t & 63;
    int sk0 = (t >> 6) * 16;
    int gn = nbase + sn; if (gn >= N) gn = N - 1;
#pragma unroll
    for (int i = 0; i < 4; ++i) {
        float4 v = *(const float4*)&X[(size_t)gn * 64 + sk0 + 4 * i];
        Xs[(sk0 + 4 * i + 0) * 65 + sn] = v.x;
        Xs[(sk0 + 4 * i + 1) * 65 + sn] = v.y;
        Xs[(sk0 + 4 * i + 2) * 65 + sn] = v.z;
        Xs[(sk0 + 4 * i + 3) * 65 + sn] = v.w;
    }
    __syncthreads();

    float a0[16], a1[16];
#pragma unroll
    for (int i = 0; i < 16; ++i) { a0[i] = 0.f; a1[i] = 0.f; }

#pragma unroll 2
    for (int k = 0; k < 64; ++k) {
        float x0 = Xs[k * 65 + ln0];
        float x1 = Xs[k * 65 + ln1];
        const float4* wr = (const float4*)&Wl[k * 128 + c0];
#pragma unroll
        for (int q = 0; q < 4; ++q) {
            float4 w = wr[q];
            a0[4 * q + 0] += x0 * w.x; a0[4 * q + 1] += x0 * w.y; a0[4 * q + 2] += x0 * w.z; a0[4 * q + 3] += x0 * w.w;
            a1[4 * q + 0] += x1 * w.x; a1[4 * q + 1] += x1 * w.y; a1[4 * q + 2] += x1 * w.z; a1[4 * q + 3] += x1 * w.w;
        }
    }

    int n0 = nbase + ln0, n1 = nbase + ln1;
    if (c0 < 64) {               // band -> md (bf16 only; e2 reads only bf16)
        if (n0 < N) {
#pragma unroll
            for (int q = 0; q < 4; ++q) {
                ushort4 u = { bfb(a0[4 * q]), bfb(a0[4 * q + 1]), bfb(a0[4 * q + 2]), bfb(a0[4 * q + 3]) };
                *(ushort4*)&md[(size_t)n0 * 64 + c0 + 4 * q] = u;
            }
        }
        if (n1 < N) {
#pragma unroll
            for (int q = 0; q < 4; ++q) {
                ushort4 u = { bfb(a1[4 * q]), bfb(a1[4 * q + 1]), bfb(a1[4 * q + 2]), bfb(a1[4 * q + 3]) };
                *(ushort4*)&md[(size_t)n1 * 64 + c0 + 4 * q] = u;
            }
        }
    } else {                     // band -> pbuf (+ bias)
        int cc = c0 - 64;
        float bb[16];
#pragma unroll
        for (int i = 0; i < 16; ++i) bb[i] = bt[cc + i] + bp[cc + i];
        if (n0 < N) {
#pragma unroll
            for (int q = 0; q < 4; ++q) {
                float4 r = { a0[4 * q] + bb[4 * q], a0[4 * q + 1] + bb[4 * q + 1], a0[4 * q + 2] + bb[4 * q + 2], a0[4 * q + 3] + bb[4 * q + 3] };
                *(float4*)&pbuf[(size_t)n0 * 64 + cc + 4 * q] = r;
            }
        }
        if (n1 < N) {
#pragma unroll
            for (int q = 0; q < 4; ++q) {
                float4 r = { a1[4 * q] + bb[4 * q], a1[4 * q + 1] + bb[4 * q + 1], a1[4 * q + 2] + bb[4 * q + 2], a1[4 * q + 3] + bb[4 * q + 3] };
                *(float4*)&pbuf[(size_t)n1 * 64 + cc + 4 * q] = r;
            }
        }
    }
}

// ---------------- EdgeConv stage 2, PAIRED-EDGE bf16 gather ----------------

__global__ __launch_bounds__(256) void k_e2_b(const unsigned short* __restrict__ md, const float* __restrict__ pbuf,
                                              const int* __restrict__ row_off, const int* __restrict__ csr,
                                              const float* __restrict__ dinv, float* __restrict__ out,
                                              unsigned short* __restrict__ outd, int N) {
    int node = blockIdx.x * 4 + (threadIdx.x >> 6);
    if (node >= N) return;
    int lane = threadIdx.x & 63;
    int sub = lane >> 5;
    int c2 = (lane & 31) * 2;
    int beg = row_off[node], end = row_off[node + 1];
    float ax = -INFINITY, ay = -INFINITY, bx = -INFINITY, by = -INFINITY;
    int j = beg;
    for (; j + 3 < end; j += 4) {
        int sA = csr[j + sub];
        int sB = csr[j + 2 + sub];
        ushort2 xA = *(const ushort2*)&md[sA * 64 + c2];
        ushort2 xB = *(const ushort2*)&md[sB * 64 + c2];
        ax = fmaxf(ax, -bf2f(xA.x)); ay = fmaxf(ay, -bf2f(xA.y));
        bx = fmaxf(bx, -bf2f(xB.x)); by = fmaxf(by, -bf2f(xB.y));
    }
    for (; j + 1 < end; j += 2) {
        int sA = csr[j + sub];
        ushort2 xA = *(const ushort2*)&md[sA * 64 + c2];
        ax = fmaxf(ax, -bf2f(xA.x)); ay = fmaxf(ay, -bf2f(xA.y));
    }
    if (j < end && sub == 0) {
        int sA = csr[j];
        ushort2 xA = *(const ushort2*)&md[sA * 64 + c2];
        ax = fmaxf(ax, -bf2f(xA.x)); ay = fmaxf(ay, -bf2f(xA.y));
    }
    float fx = fmaxf(ax, bx), fy = fmaxf(ay, by);
    fx = fmaxf(fx, __shfl_xor(fx, 32));
    fy = fmaxf(fy, __shfl_xor(fy, 32));
    if (sub == 0) {
        float rx = 0.f, ry = 0.f;
        if (end > beg) {
            float2 pv = *(const float2*)&pbuf[(size_t)node * 64 + c2];
            rx = fmaxf(pv.x + fx, 0.f);
            ry = fmaxf(pv.y + fy, 0.f);
        }
        float2 r = { rx, ry };
        *(float2*)&out[(size_t)node * 64 + c2] = r;
        float dn = dinv[node];
        ushort2 u = { bfb(rx * dn), bfb(ry * dn) };
        *(ushort2*)&outd[(size_t)node * 64 + c2] = u;
    }
}

// ---------------- graph mean pooling (segmented: gid is sorted) ----------------

__global__ __launch_bounds__(256) void k_pool(const float* __restrict__ h, const int* __restrict__ gid,
                                              float* __restrict__ out, float* __restrict__ gcnt, int N) {
    const int CHUNK = 128;
    int wave = blockIdx.x * 4 + (threadIdx.x >> 6);
    int lane = threadIdx.x & 63;
    int beg = wave * CHUNK;
    if (beg >= N) return;
    int end = beg + CHUNK < N ? beg + CHUNK : N;
    int gcur = gid[beg];
    float acc = 0.f;
    int cnt = 0;
    for (int n = beg; n < end; ++n) {
        int g = gid[n];
        float v = h[n * 64 + lane];
        if (g != gcur) {
            atomicAdd(&out[gcur * 64 + lane], acc);
            if (lane == 0) atomicAdd(&gcnt[gcur], (float)cnt);
            gcur = g; acc = 0.f; cnt = 0;
        }
        acc += v;
        ++cnt;
    }
    atomicAdd(&out[gcur * 64 + lane], acc);
    if (lane == 0) atomicAdd(&gcnt[gcur], (float)cnt);
}

__global__ __launch_bounds__(256) void k_div(float* __restrict__ out, const float* __restrict__ gcnt, int total) {
    int i = blockIdx.x * blockDim.x + threadIdx.x;
    if (i < total) out[i] /= fmaxf(gcnt[i >> 6], 1.f);
}

// ---------------- launcher ----------------

extern "C" void kernel_launch(void* const* d_in, const int* in_sizes, int n_in,
                              void* d_out, int out_size, void* d_ws, size_t ws_size,
                              hipStream_t stream) {
    const float* feat = (const float*)d_in[0];
    const int* src = (const int*)d_in[1];
    const int* dst = (const int*)d_in[2];
    const int* gid = (const int*)d_in[3];
    const float* W1 = (const float*)d_in[4];  const float* b1 = (const float*)d_in[5];
    const float* W2 = (const float*)d_in[6];  const float* b2 = (const float*)d_in[7];
    const float* W3 = (const float*)d_in[8];  const float* b3 = (const float*)d_in[9];
    const float* Wt1 = (const float*)d_in[10]; const float* bt1 = (const float*)d_in[11];
    const float* Wp1 = (const float*)d_in[12]; const float* bp1 = (const float*)d_in[13];
    const float* Wt2 = (const float*)d_in[14]; const float* bt2 = (const float*)d_in[15];
    const float* Wp2 = (const float*)d_in[16]; const float* bp2 = (const float*)d_in[17];
    float* out = (float*)d_out;

    const int N = in_sizes[0] / 16;
    const int E = in_sizes[1];
    const int G = out_size / 64;

    char* p = (char*)d_ws;
    auto alloc = [&](size_t nbytes) {
        void* r = (void*)p;
        p += (nbytes + 255) & ~(size_t)255;
        return r;
    };
    int* cnt      = (int*)alloc((size_t)N * 4);
    int* row_off  = (int*)alloc((size_t)(N + 1) * 4);
    int* cursor   = (int*)alloc((size_t)N * 4);
    int* csr      = (int*)alloc((size_t)E * 4);
    int* bsum     = (int*)alloc(512 * 4);
    float* dinv   = (float*)alloc((size_t)N * 4);
    float* bufA   = (float*)alloc((size_t)N * 64 * 4);
    float* bufB   = (float*)alloc((size_t)N * 64 * 4);
    float* bufC   = (float*)alloc((size_t)N * 64 * 4);
    float* bufD   = (float*)alloc((size_t)N * 64 * 4);
    unsigned short* md = (unsigned short*)alloc((size_t)N * 64 * 2);
    float* gcnt   = (float*)alloc((size_t)G * 4);

    // bf16 scratch in bufC's dead windows (dead when cheb_t writes bufC; e1 consumes bufC before e2 writes hd)
    unsigned short* hd = (unsigned short*)bufC;
    unsigned short* xd = (unsigned short*)bufC + (size_t)N * 64;

    hipMemsetAsync(cnt, 0, (size_t)N * 4, stream);
    hipMemsetAsync(gcnt, 0, (size_t)G * 4, stream);
    hipMemsetAsync(d_out, 0, (size_t)out_size * 4, stream);

    const int B = (N + 255) / 256;
    const int ebk = (E + 255) / 256;
    const int nb16 = (N * 16 + 255) / 256;
    const int nbw = (N + 3) / 4;       // wave-per-node paired gathers
    const int npool = ((N + 127) / 128 + 3) / 4;
    const int nbt = (N + 63) / 64;

    k_hist<<<ebk, 256, 0, stream>>>(dst, cnt, E);
    k_scanA<<<B, 256, 0, stream>>>(cnt, bsum, N);
    k_scanB<<<1, 512, 0, stream>>>(bsum, B);
    k_scanC<<<B, 256, 0, stream>>>(cnt, bsum, row_off, cursor, dinv, N, E);
    k_scatter<<<ebk, 256, 0, stream>>>(src, dst, cursor, csr, E);

    // ---- Cheb layer 1 (IN=16): featd = feat*dinv (bf16, in hd slot)
    k_feat16<<<nb16, 256, 0, stream>>>(feat, dinv, hd, N * 16);
    k_aggr16<<<nb16, 256, 0, stream>>>(hd, nullptr, dinv, row_off, csr, bufA, xd, -1.f, 0.f, N);
    k_aggr16<<<nb16, 256, 0, stream>>>(xd, feat, dinv, row_off, csr, bufB, nullptr, -2.f, -1.f, N);
    k_cheb_t<16><<<nbt, 256, 0, stream>>>(feat, bufA, bufB, W1, b1, bufC, N);

    // ---- EdgeConv 1
    k_e1_t<<<nbt, 256, 0, stream>>>(bufC, Wt1, Wp1, bt1, bp1, md, bufB, N);
    k_e2_b<<<nbw, 256, 0, stream>>>(md, bufB, row_off, csr, dinv, bufD, hd, N);

    // ---- Cheb layer 2
    k_aggr64<<<nbw, 256, 0, stream>>>(hd, nullptr, dinv, row_off, csr, bufA, xd, -1.f, 0.f, N);
    k_aggr64<<<nbw, 256, 0, stream>>>(xd, bufD, dinv, row_off, csr, bufB, nullptr, -2.f, -1.f, N);
    k_cheb_t<64><<<nbt, 256, 0, stream>>>(bufD, bufA, bufB, W2, b2, bufC, N);

    // ---- EdgeConv 2
    k_e1_t<<<nbt, 256, 0, stream>>>(bufC, Wt2, Wp2, bt2, bp2, md, bufB, N);
    k_e2_b<<<nbw, 256, 0, stream>>>(md, bufB, row_off, csr, dinv, bufD, hd, N);

    // ---- Cheb layer 3
    k_aggr64<<<nbw, 256, 0, stream>>>(hd, nullptr, dinv, row_off, csr, bufA, xd, -1.f, 0.f, N);
    k_aggr64<<<nbw, 256, 0, stream>>>(xd, bufD, dinv, row_off, csr, bufB, nullptr, -2.f, -1.f, N);
    k_cheb_t<64><<<nbt, 256, 0, stream>>>(bufD, bufA, bufB, W3, b3, bufC, N);

    // ---- per-graph mean pooling
    k_pool<<<npool, 256, 0, stream>>>(bufC, gid, out, gcnt, N);
    k_div<<<(out_size + 255) / 256, 256, 0, stream>>>(out, gcnt, out_size);
}

// Round 10
// 750.962 us; speedup vs baseline: 1.9252x; 1.2706x over previous
//
#include <hip/hip_runtime.h>
#include <hip/hip_bf16.h>
#include <math.h>

__device__ __forceinline__ unsigned short bfb(float x) {
    union { __hip_bfloat16 h; unsigned short u; } c;
    c.h = __float2bfloat16(x);
    return c.u;
}
__device__ __forceinline__ float bf2f(unsigned short u) {
    union { unsigned int i; float f; } c;
    c.i = ((unsigned int)u) << 16;
    return c.f;
}

// ---------------- bucketed CSR build v2 ----------------
// bucket = dst>>8 (256 nodes). R6 k_scatter wrote 105MB for 6.4MB (random 4B stores,
// cross-XCD partial lines). R7 k_part died on per-EDGE global atomics (4100/cursor).
// v2: per-BLOCK LDS histogram + one reservation atomic per (block,bucket) [76k total,
// ~196/address], then append into block-owned contiguous spans.

__global__ __launch_bounds__(256) void k_bhist(const int* __restrict__ dst, int* __restrict__ bcnt, int E) {
    __shared__ int h[512];
    int t = threadIdx.x;
    for (int i = t; i < 512; i += 256) h[i] = 0;
    __syncthreads();
    int step = gridDim.x * 256;
    for (int i = blockIdx.x * 256 + t; i < E; i += step) atomicAdd(&h[dst[i] >> 8], 1);
    __syncthreads();
    for (int i = t; i < 512; i += 256) if (h[i]) atomicAdd(&bcnt[i], h[i]);
}

__global__ __launch_bounds__(512) void k_scanBkt(const int* __restrict__ bcnt, int* __restrict__ boff,
                                                 int* __restrict__ bcur, int nb, int E) {
    __shared__ int s[512];
    int t = threadIdx.x;
    int v = (t < nb) ? bcnt[t] : 0;
    s[t] = v;
    __syncthreads();
    for (int off = 1; off < 512; off <<= 1) {
        int x = (t >= off) ? s[t - off] : 0;
        __syncthreads();
        s[t] += x;
        __syncthreads();
    }
    if (t < nb) { boff[t] = s[t] - v; bcur[t] = s[t] - v; }
    if (t == 0) boff[nb] = E;
}

#define PCHUNK 8192

__global__ __launch_bounds__(256) void k_partA(const int* __restrict__ src, const int* __restrict__ dst,
                                               int* __restrict__ bcur, uint2* __restrict__ ebuf, int E) {
    __shared__ int h[512];
    __shared__ int base[512];
    int t = threadIdx.x;
    for (int i = t; i < 512; i += 256) h[i] = 0;
    __syncthreads();
    int start = blockIdx.x * PCHUNK;
    int end = start + PCHUNK < E ? start + PCHUNK : E;
    for (int i = start + t; i < end; i += 256) atomicAdd(&h[dst[i] >> 8], 1);
    __syncthreads();
    for (int i = t; i < 512; i += 256) {
        int c = h[i];
        base[i] = c ? atomicAdd(&bcur[i], c) : 0;
        h[i] = 0;
    }
    __syncthreads();
    for (int i = start + t; i < end; i += 256) {
        int d = dst[i];
        int b = d >> 8;
        int r = atomicAdd(&h[b], 1);
        ebuf[base[b] + r] = make_uint2((unsigned)src[i], (unsigned)d);
    }
}

__global__ __launch_bounds__(256) void k_cnt(const uint2* __restrict__ ebuf, const int* __restrict__ boff,
                                             int* __restrict__ cnt, int N) {
    __shared__ int h[256];
    int b = blockIdx.x, t = threadIdx.x;
    h[t] = 0;
    __syncthreads();
    int beg = boff[b], end = boff[b + 1];
    for (int e = beg + t; e < end; e += 256) atomicAdd(&h[ebuf[e].y & 255], 1);
    __syncthreads();
    int node = (b << 8) + t;
    if (node < N) cnt[node] = h[t];
}

__global__ __launch_bounds__(256) void k_scanA(const int* __restrict__ cnt, int* __restrict__ bsum, int N) {
    __shared__ int s[256];
    int t = threadIdx.x;
    int i = blockIdx.x * 256 + t;
    s[t] = (i < N) ? cnt[i] : 0;
    __syncthreads();
    for (int off = 128; off > 0; off >>= 1) {
        if (t < off) s[t] += s[t + off];
        __syncthreads();
    }
    if (t == 0) bsum[blockIdx.x] = s[0];
}

__global__ __launch_bounds__(512) void k_scanB(int* __restrict__ bsum, int B) {
    __shared__ int s[512];
    int t = threadIdx.x;
    int v = (t < B) ? bsum[t] : 0;
    s[t] = v;
    __syncthreads();
    for (int off = 1; off < 512; off <<= 1) {
        int x = (t >= off) ? s[t - off] : 0;
        __syncthreads();
        s[t] += x;
        __syncthreads();
    }
    if (t < B) bsum[t] = s[t] - v;   // exclusive
}

__global__ __launch_bounds__(256) void k_scanC(const int* __restrict__ cnt, const int* __restrict__ bsum,
                                               int* __restrict__ row_off, float* __restrict__ dinv, int N, int E) {
    __shared__ int s[256];
    int t = threadIdx.x;
    int i = blockIdx.x * 256 + t;
    int v = (i < N) ? cnt[i] : 0;
    s[t] = v;
    __syncthreads();
    for (int off = 1; off < 256; off <<= 1) {
        int x = (t >= off) ? s[t - off] : 0;
        __syncthreads();
        s[t] += x;
        __syncthreads();
    }
    if (i < N) {
        int excl = bsum[blockIdx.x] + s[t] - v;
        row_off[i] = excl;
        dinv[i]    = rsqrtf((float)(v > 1 ? v : 1));
    }
    if (i == 0) row_off[N] = E;
}

__global__ __launch_bounds__(256) void k_scat2(const uint2* __restrict__ ebuf, const int* __restrict__ boff,
                                               const int* __restrict__ row_off, int* __restrict__ csr, int N) {
    __shared__ int cur[256];
    int b = blockIdx.x, t = threadIdx.x;
    int node = (b << 8) + t;
    cur[t] = (node < N) ? row_off[node] : 0;
    __syncthreads();
    int beg = boff[b], end = boff[b + 1];
    for (int e = beg + t; e < end; e += 256) {
        uint2 ed = ebuf[e];
        int pos = atomicAdd(&cur[ed.y & 255], 1);
        csr[pos] = (int)ed.x;
    }
}

// ---------------- feat -> bf16 pre-scaled (featd = feat * dinv) ----------------

__global__ __launch_bounds__(256) void k_feat16(const float* __restrict__ feat, const float* __restrict__ dinv,
                                                unsigned short* __restrict__ featd, int total) {
    int i = blockIdx.x * 256 + threadIdx.x;
    if (i < total) featd[i] = bfb(feat[i] * dinv[i >> 4]);
}

// ---------------- 16-dim Chebyshev aggregation (bf16 gather, scalar layout) ----------------

__global__ __launch_bounds__(256) void k_aggr16(const unsigned short* __restrict__ Xd, const float* __restrict__ Z,
                                                const float* __restrict__ dinv,
                                                const int* __restrict__ row_off, const int* __restrict__ csr,
                                                float* __restrict__ out, unsigned short* __restrict__ outd,
                                                float alpha, float beta, int N) {
    const int D = 16;
    int t = blockIdx.x * blockDim.x + threadIdx.x;
    int node = t / D;
    int d = t % D;
    if (node >= N) return;
    int beg = row_off[node], end = row_off[node + 1];
    float a0 = 0.f, a1 = 0.f, a2 = 0.f, a3 = 0.f;
    int j = beg;
    for (; j + 3 < end; j += 4) {
        int s0 = csr[j], s1 = csr[j + 1], s2 = csr[j + 2], s3 = csr[j + 3];
        a0 += bf2f(Xd[s0 * D + d]);
        a1 += bf2f(Xd[s1 * D + d]);
        a2 += bf2f(Xd[s2 * D + d]);
        a3 += bf2f(Xd[s3 * D + d]);
    }
    for (; j < end; ++j) a0 += bf2f(Xd[csr[j] * D + d]);
    float acc = (a0 + a1) + (a2 + a3);
    float dn = dinv[node];
    float v = alpha * dn * acc;
    if (Z) v += beta * Z[node * D + d];
    out[node * D + d] = v;
    if (outd) outd[node * D + d] = bfb(v * dn);
}

// ---------------- 64-dim Chebyshev aggregation, 8-wide paired-edge gather ----------------
// Wave = node; half-waves split edges; each lane loads ushort2 (dims 2c,2c+1).
// 8 edges per iteration = 4 independent loads in flight per half-wave (MLP x2 vs R9).

__global__ __launch_bounds__(256) void k_aggr64(const unsigned short* __restrict__ Xd, const float* __restrict__ Z,
                                                const float* __restrict__ dinv,
                                                const int* __restrict__ row_off, const int* __restrict__ csr,
                                                float* __restrict__ out, unsigned short* __restrict__ outd,
                                                float alpha, float beta, int N) {
    int node = blockIdx.x * 4 + (threadIdx.x >> 6);
    if (node >= N) return;
    int lane = threadIdx.x & 63;
    int sub = lane >> 5;
    int c2 = (lane & 31) * 2;
    int beg = row_off[node], end = row_off[node + 1];
    float ax = 0.f, ay = 0.f, bx = 0.f, by = 0.f;
    float cx = 0.f, cy = 0.f, dx = 0.f, dy = 0.f;
    int j = beg;
    for (; j + 7 < end; j += 8) {
        int s0 = csr[j + sub];
        int s1 = csr[j + 2 + sub];
        int s2 = csr[j + 4 + sub];
        int s3 = csr[j + 6 + sub];
        ushort2 x0 = *(const ushort2*)&Xd[s0 * 64 + c2];
        ushort2 x1 = *(const ushort2*)&Xd[s1 * 64 + c2];
        ushort2 x2 = *(const ushort2*)&Xd[s2 * 64 + c2];
        ushort2 x3 = *(const ushort2*)&Xd[s3 * 64 + c2];
        ax += bf2f(x0.x); ay += bf2f(x0.y);
        bx += bf2f(x1.x); by += bf2f(x1.y);
        cx += bf2f(x2.x); cy += bf2f(x2.y);
        dx += bf2f(x3.x); dy += bf2f(x3.y);
    }
    for (; j + 3 < end; j += 4) {
        int s0 = csr[j + sub];
        int s1 = csr[j + 2 + sub];
        ushort2 x0 = *(const ushort2*)&Xd[s0 * 64 + c2];
        ushort2 x1 = *(const ushort2*)&Xd[s1 * 64 + c2];
        ax += bf2f(x0.x); ay += bf2f(x0.y);
        bx += bf2f(x1.x); by += bf2f(x1.y);
    }
    for (; j + 1 < end; j += 2) {
        int s0 = csr[j + sub];
        ushort2 x0 = *(const ushort2*)&Xd[s0 * 64 + c2];
        ax += bf2f(x0.x); ay += bf2f(x0.y);
    }
    if (j < end && sub == 0) {
        int s0 = csr[j];
        ushort2 x0 = *(const ushort2*)&Xd[s0 * 64 + c2];
        ax += bf2f(x0.x); ay += bf2f(x0.y);
    }
    float fx = (ax + bx) + (cx + dx);
    float fy = (ay + by) + (cy + dy);
    fx += __shfl_xor(fx, 32);
    fy += __shfl_xor(fy, 32);
    if (sub == 0) {
        float dn = dinv[node];
        float vx = alpha * dn * fx;
        float vy = alpha * dn * fy;
        if (Z) {
            float2 zv = *(const float2*)&Z[(size_t)node * 64 + c2];
            vx += beta * zv.x;
            vy += beta * zv.y;
        }
        float2 r = { vx, vy };
        *(float2*)&out[(size_t)node * 64 + c2] = r;
        if (outd) {
            ushort2 u = { bfb(vx * dn), bfb(vy * dn) };
            *(ushort2*)&outd[(size_t)node * 64 + c2] = u;
        }
    }
}

// ---------------- Cheb matmul, LDS-tiled GEMM (unroll capped: R5 full-unroll spilled) ----------------

template <int KDIM>
__global__ __launch_bounds__(256) void k_cheb_t(const float* __restrict__ X0, const float* __restrict__ X1,
                                                const float* __restrict__ X2, const float* __restrict__ W,
                                                const float* __restrict__ b, float* __restrict__ out, int N) {
    __shared__ float Ws[3 * KDIM * 64];
    __shared__ float Xs[KDIM * 65];
    int t = threadIdx.x;
    for (int idx = t; idx < 3 * KDIM * 64; idx += 256) Ws[idx] = W[idx];

    int nbase = blockIdx.x * 64;
    int ln0 = t & 31;
    int ln1 = 32 + ln0;
    int c0  = (t >> 5) * 8;

    int sn  = t & 63;
    int sk0 = (t >> 6) * (KDIM / 4);
    int gn  = nbase + sn; if (gn >= N) gn = N - 1;

    float a0[8], a1[8];
#pragma unroll
    for (int i = 0; i < 8; ++i) { a0[i] = 0.f; a1[i] = 0.f; }

    const float* Xp[3] = { X0, X1, X2 };
#pragma unroll 1
    for (int a = 0; a < 3; ++a) {
        const float* X = Xp[a];
        __syncthreads();
#pragma unroll
        for (int i = 0; i < KDIM / 16; ++i) {
            float4 v = *(const float4*)&X[(size_t)gn * KDIM + sk0 + 4 * i];
            Xs[(sk0 + 4 * i + 0) * 65 + sn] = v.x;
            Xs[(sk0 + 4 * i + 1) * 65 + sn] = v.y;
            Xs[(sk0 + 4 * i + 2) * 65 + sn] = v.z;
            Xs[(sk0 + 4 * i + 3) * 65 + sn] = v.w;
        }
        __syncthreads();
#pragma unroll 4
        for (int k = 0; k < KDIM; ++k) {
            float x0 = Xs[k * 65 + ln0];
            float x1 = Xs[k * 65 + ln1];
            const float4* wr = (const float4*)&Ws[(a * KDIM + k) * 64 + c0];
            float4 wA = wr[0];
            float4 wB = wr[1];
            a0[0] += x0 * wA.x; a0[1] += x0 * wA.y; a0[2] += x0 * wA.z; a0[3] += x0 * wA.w;
            a0[4] += x0 * wB.x; a0[5] += x0 * wB.y; a0[6] += x0 * wB.z; a0[7] += x0 * wB.w;
            a1[0] += x1 * wA.x; a1[1] += x1 * wA.y; a1[2] += x1 * wA.z; a1[3] += x1 * wA.w;
            a1[4] += x1 * wB.x; a1[5] += x1 * wB.y; a1[6] += x1 * wB.z; a1[7] += x1 * wB.w;
        }
    }

    float4 bA = *(const float4*)&b[c0];
    float4 bB = *(const float4*)&b[c0 + 4];
    int n0 = nbase + ln0, n1 = nbase + ln1;
    if (n0 < N) {
        float4 r0 = { fmaxf(a0[0] + bA.x, 0.f), fmaxf(a0[1] + bA.y, 0.f), fmaxf(a0[2] + bA.z, 0.f), fmaxf(a0[3] + bA.w, 0.f) };
        float4 r1 = { fmaxf(a0[4] + bB.x, 0.f), fmaxf(a0[5] + bB.y, 0.f), fmaxf(a0[6] + bB.z, 0.f), fmaxf(a0[7] + bB.w, 0.f) };
        *(float4*)&out[(size_t)n0 * 64 + c0] = r0;
        *(float4*)&out[(size_t)n0 * 64 + c0 + 4] = r1;
    }
    if (n1 < N) {
        float4 r0 = { fmaxf(a1[0] + bA.x, 0.f), fmaxf(a1[1] + bA.y, 0.f), fmaxf(a1[2] + bA.z, 0.f), fmaxf(a1[3] + bA.w, 0.f) };
        float4 r1 = { fmaxf(a1[4] + bB.x, 0.f), fmaxf(a1[5] + bB.y, 0.f), fmaxf(a1[6] + bB.z, 0.f), fmaxf(a1[7] + bB.w, 0.f) };
        *(float4*)&out[(size_t)n1 * 64 + c0] = r0;
        *(float4*)&out[(size_t)n1 * 64 + c0 + 4] = r1;
    }
}

// ---------------- EdgeConv stage 1 as tiled GEMM: [m|p] = X @ [Wt | Wt+Wp]; m emitted as bf16 ----------------

__global__ __launch_bounds__(256) void k_e1_t(const float* __restrict__ X, const float* __restrict__ Wt,
                                              const float* __restrict__ Wp, const float* __restrict__ bt,
                                              const float* __restrict__ bp,
                                              unsigned short* __restrict__ md, float* __restrict__ pbuf, int N) {
    __shared__ float Wl[64 * 128];
    __shared__ float Xs[64 * 65];
    int t = threadIdx.x;
    for (int idx = t; idx < 64 * 64; idx += 256) {
        int k = idx >> 6, c = idx & 63;
        float wt = Wt[idx];
        Wl[k * 128 + c] = wt;
        Wl[k * 128 + 64 + c] = wt + Wp[idx];
    }

    int nbase = blockIdx.x * 64;
    int ln0 = t & 31, ln1 = 32 + ln0;
    int c0 = (t >> 5) * 16;

    int sn = t & 63;
    int sk0 = (t >> 6) * 16;
    int gn = nbase + sn; if (gn >= N) gn = N - 1;
#pragma unroll
    for (int i = 0; i < 4; ++i) {
        float4 v = *(const float4*)&X[(size_t)gn * 64 + sk0 + 4 * i];
        Xs[(sk0 + 4 * i + 0) * 65 + sn] = v.x;
        Xs[(sk0 + 4 * i + 1) * 65 + sn] = v.y;
        Xs[(sk0 + 4 * i + 2) * 65 + sn] = v.z;
        Xs[(sk0 + 4 * i + 3) * 65 + sn] = v.w;
    }
    __syncthreads();

    float a0[16], a1[16];
#pragma unroll
    for (int i = 0; i < 16; ++i) { a0[i] = 0.f; a1[i] = 0.f; }

#pragma unroll 2
    for (int k = 0; k < 64; ++k) {
        float x0 = Xs[k * 65 + ln0];
        float x1 = Xs[k * 65 + ln1];
        const float4* wr = (const float4*)&Wl[k * 128 + c0];
#pragma unroll
        for (int q = 0; q < 4; ++q) {
            float4 w = wr[q];
            a0[4 * q + 0] += x0 * w.x; a0[4 * q + 1] += x0 * w.y; a0[4 * q + 2] += x0 * w.z; a0[4 * q + 3] += x0 * w.w;
            a1[4 * q + 0] += x1 * w.x; a1[4 * q + 1] += x1 * w.y; a1[4 * q + 2] += x1 * w.z; a1[4 * q + 3] += x1 * w.w;
        }
    }

    int n0 = nbase + ln0, n1 = nbase + ln1;
    if (c0 < 64) {               // band -> md (bf16 only)
        if (n0 < N) {
#pragma unroll
            for (int q = 0; q < 4; ++q) {
                ushort4 u = { bfb(a0[4 * q]), bfb(a0[4 * q + 1]), bfb(a0[4 * q + 2]), bfb(a0[4 * q + 3]) };
                *(ushort4*)&md[(size_t)n0 * 64 + c0 + 4 * q] = u;
            }
        }
        if (n1 < N) {
#pragma unroll
            for (int q = 0; q < 4; ++q) {
                ushort4 u = { bfb(a1[4 * q]), bfb(a1[4 * q + 1]), bfb(a1[4 * q + 2]), bfb(a1[4 * q + 3]) };
                *(ushort4*)&md[(size_t)n1 * 64 + c0 + 4 * q] = u;
            }
        }
    } else {                     // band -> pbuf (+ bias)
        int cc = c0 - 64;
        float bb[16];
#pragma unroll
        for (int i = 0; i < 16; ++i) bb[i] = bt[cc + i] + bp[cc + i];
        if (n0 < N) {
#pragma unroll
            for (int q = 0; q < 4; ++q) {
                float4 r = { a0[4 * q] + bb[4 * q], a0[4 * q + 1] + bb[4 * q + 1], a0[4 * q + 2] + bb[4 * q + 2], a0[4 * q + 3] + bb[4 * q + 3] };
                *(float4*)&pbuf[(size_t)n0 * 64 + cc + 4 * q] = r;
            }
        }
        if (n1 < N) {
#pragma unroll
            for (int q = 0; q < 4; ++q) {
                float4 r = { a1[4 * q] + bb[4 * q], a1[4 * q + 1] + bb[4 * q + 1], a1[4 * q + 2] + bb[4 * q + 2], a1[4 * q + 3] + bb[4 * q + 3] };
                *(float4*)&pbuf[(size_t)n1 * 64 + cc + 4 * q] = r;
            }
        }
    }
}

// ---------------- EdgeConv stage 2, 8-wide paired-edge bf16 gather ----------------

__global__ __launch_bounds__(256) void k_e2_b(const unsigned short* __restrict__ md, const float* __restrict__ pbuf,
                                              const int* __restrict__ row_off, const int* __restrict__ csr,
                                              const float* __restrict__ dinv, float* __restrict__ out,
                                              unsigned short* __restrict__ outd, int N) {
    int node = blockIdx.x * 4 + (threadIdx.x >> 6);
    if (node >= N) return;
    int lane = threadIdx.x & 63;
    int sub = lane >> 5;
    int c2 = (lane & 31) * 2;
    int beg = row_off[node], end = row_off[node + 1];
    float ax = -INFINITY, ay = -INFINITY, bx = -INFINITY, by = -INFINITY;
    float cx = -INFINITY, cy = -INFINITY, dx = -INFINITY, dy = -INFINITY;
    int j = beg;
    for (; j + 7 < end; j += 8) {
        int s0 = csr[j + sub];
        int s1 = csr[j + 2 + sub];
        int s2 = csr[j + 4 + sub];
        int s3 = csr[j + 6 + sub];
        ushort2 x0 = *(const ushort2*)&md[s0 * 64 + c2];
        ushort2 x1 = *(const ushort2*)&md[s1 * 64 + c2];
        ushort2 x2 = *(const ushort2*)&md[s2 * 64 + c2];
        ushort2 x3 = *(const ushort2*)&md[s3 * 64 + c2];
        ax = fmaxf(ax, -bf2f(x0.x)); ay = fmaxf(ay, -bf2f(x0.y));
        bx = fmaxf(bx, -bf2f(x1.x)); by = fmaxf(by, -bf2f(x1.y));
        cx = fmaxf(cx, -bf2f(x2.x)); cy = fmaxf(cy, -bf2f(x2.y));
        dx = fmaxf(dx, -bf2f(x3.x)); dy = fmaxf(dy, -bf2f(x3.y));
    }
    for (; j + 3 < end; j += 4) {
        int s0 = csr[j + sub];
        int s1 = csr[j + 2 + sub];
        ushort2 x0 = *(const ushort2*)&md[s0 * 64 + c2];
        ushort2 x1 = *(const ushort2*)&md[s1 * 64 + c2];
        ax = fmaxf(ax, -bf2f(x0.x)); ay = fmaxf(ay, -bf2f(x0.y));
        bx = fmaxf(bx, -bf2f(x1.x)); by = fmaxf(by, -bf2f(x1.y));
    }
    for (; j + 1 < end; j += 2) {
        int s0 = csr[j + sub];
        ushort2 x0 = *(const ushort2*)&md[s0 * 64 + c2];
        ax = fmaxf(ax, -bf2f(x0.x)); ay = fmaxf(ay, -bf2f(x0.y));
    }
    if (j < end && sub == 0) {
        int s0 = csr[j];
        ushort2 x0 = *(const ushort2*)&md[s0 * 64 + c2];
        ax = fmaxf(ax, -bf2f(x0.x)); ay = fmaxf(ay, -bf2f(x0.y));
    }
    float fx = fmaxf(fmaxf(ax, bx), fmaxf(cx, dx));
    float fy = fmaxf(fmaxf(ay, by), fmaxf(cy, dy));
    fx = fmaxf(fx, __shfl_xor(fx, 32));
    fy = fmaxf(fy, __shfl_xor(fy, 32));
    if (sub == 0) {
        float rx = 0.f, ry = 0.f;
        if (end > beg) {
            float2 pv = *(const float2*)&pbuf[(size_t)node * 64 + c2];
            rx = fmaxf(pv.x + fx, 0.f);
            ry = fmaxf(pv.y + fy, 0.f);
        }
        float2 r = { rx, ry };
        *(float2*)&out[(size_t)node * 64 + c2] = r;
        float dn = dinv[node];
        ushort2 u = { bfb(rx * dn), bfb(ry * dn) };
        *(ushort2*)&outd[(size_t)node * 64 + c2] = u;
    }
}

// ---------------- graph mean pooling (segmented: gid is sorted) ----------------

__global__ __launch_bounds__(256) void k_pool(const float* __restrict__ h, const int* __restrict__ gid,
                                              float* __restrict__ out, float* __restrict__ gcnt, int N) {
    const int CHUNK = 128;
    int wave = blockIdx.x * 4 + (threadIdx.x >> 6);
    int lane = threadIdx.x & 63;
    int beg = wave * CHUNK;
    if (beg >= N) return;
    int end = beg + CHUNK < N ? beg + CHUNK : N;
    int gcur = gid[beg];
    float acc = 0.f;
    int cnt = 0;
    for (int n = beg; n < end; ++n) {
        int g = gid[n];
        float v = h[n * 64 + lane];
        if (g != gcur) {
            atomicAdd(&out[gcur * 64 + lane], acc);
            if (lane == 0) atomicAdd(&gcnt[gcur], (float)cnt);
            gcur = g; acc = 0.f; cnt = 0;
        }
        acc += v;
        ++cnt;
    }
    atomicAdd(&out[gcur * 64 + lane], acc);
    if (lane == 0) atomicAdd(&gcnt[gcur], (float)cnt);
}

__global__ __launch_bounds__(256) void k_div(float* __restrict__ out, const float* __restrict__ gcnt, int total) {
    int i = blockIdx.x * blockDim.x + threadIdx.x;
    if (i < total) out[i] /= fmaxf(gcnt[i >> 6], 1.f);
}

// ---------------- launcher ----------------

extern "C" void kernel_launch(void* const* d_in, const int* in_sizes, int n_in,
                              void* d_out, int out_size, void* d_ws, size_t ws_size,
                              hipStream_t stream) {
    const float* feat = (const float*)d_in[0];
    const int* src = (const int*)d_in[1];
    const int* dst = (const int*)d_in[2];
    const int* gid = (const int*)d_in[3];
    const float* W1 = (const float*)d_in[4];  const float* b1 = (const float*)d_in[5];
    const float* W2 = (const float*)d_in[6];  const float* b2 = (const float*)d_in[7];
    const float* W3 = (const float*)d_in[8];  const float* b3 = (const float*)d_in[9];
    const float* Wt1 = (const float*)d_in[10]; const float* bt1 = (const float*)d_in[11];
    const float* Wp1 = (const float*)d_in[12]; const float* bp1 = (const float*)d_in[13];
    const float* Wt2 = (const float*)d_in[14]; const float* bt2 = (const float*)d_in[15];
    const float* Wp2 = (const float*)d_in[16]; const float* bp2 = (const float*)d_in[17];
    float* out = (float*)d_out;

    const int N = in_sizes[0] / 16;
    const int E = in_sizes[1];
    const int G = out_size / 64;
    const int nb = (N + 255) >> 8;      // buckets (<= 512)

    char* p = (char*)d_ws;
    auto alloc = [&](size_t nbytes) {
        void* r = (void*)p;
        p += (nbytes + 255) & ~(size_t)255;
        return r;
    };
    int* cnt      = (int*)alloc((size_t)N * 4);
    int* row_off  = (int*)alloc((size_t)(N + 1) * 4);
    int* csr      = (int*)alloc((size_t)E * 4);
    int* bsum     = (int*)alloc(512 * 4);
    int* bcnt     = (int*)alloc(512 * 4);
    int* boff     = (int*)alloc(513 * 4);
    int* bcur     = (int*)alloc(512 * 4);
    float* dinv   = (float*)alloc((size_t)N * 4);
    float* bufA   = (float*)alloc((size_t)N * 64 * 4);
    float* bufB   = (float*)alloc((size_t)N * 64 * 4);
    float* bufC   = (float*)alloc((size_t)N * 64 * 4);
    float* bufD   = (float*)alloc((size_t)N * 64 * 4);
    unsigned short* md = (unsigned short*)alloc((size_t)N * 64 * 2);
    float* gcnt   = (float*)alloc((size_t)G * 4);

    uint2* ebuf = (uint2*)bufA;   // alias: bufA dead until after CSR build (E*8 <= N*256)
    unsigned short* hd = (unsigned short*)bufC;                    // bf16 scratch in bufC dead windows
    unsigned short* xd = (unsigned short*)bufC + (size_t)N * 64;

    hipMemsetAsync(bcnt, 0, 512 * 4, stream);
    hipMemsetAsync(gcnt, 0, (size_t)G * 4, stream);
    hipMemsetAsync(d_out, 0, (size_t)out_size * 4, stream);

    const int B = (N + 255) / 256;
    const int nb16 = (N * 16 + 255) / 256;
    const int nbw = (N + 3) / 4;
    const int npool = ((N + 127) / 128 + 3) / 4;
    const int nbt = (N + 63) / 64;
    const int npart = (E + PCHUNK - 1) / PCHUNK;

    // ---- bucketed CSR build v2
    k_bhist<<<256, 256, 0, stream>>>(dst, bcnt, E);
    k_scanBkt<<<1, 512, 0, stream>>>(bcnt, boff, bcur, nb, E);
    k_partA<<<npart, 256, 0, stream>>>(src, dst, bcur, ebuf, E);
    k_cnt<<<nb, 256, 0, stream>>>(ebuf, boff, cnt, N);
    k_scanA<<<B, 256, 0, stream>>>(cnt, bsum, N);
    k_scanB<<<1, 512, 0, stream>>>(bsum, B);
    k_scanC<<<B, 256, 0, stream>>>(cnt, bsum, row_off, dinv, N, E);
    k_scat2<<<nb, 256, 0, stream>>>(ebuf, boff, row_off, csr, N);

    // ---- Cheb layer 1 (IN=16): featd = feat*dinv (bf16, in hd slot)
    k_feat16<<<nb16, 256, 0, stream>>>(feat, dinv, hd, N * 16);
    k_aggr16<<<nb16, 256, 0, stream>>>(hd, nullptr, dinv, row_off, csr, bufA, xd, -1.f, 0.f, N);
    k_aggr16<<<nb16, 256, 0, stream>>>(xd, feat, dinv, row_off, csr, bufB, nullptr, -2.f, -1.f, N);
    k_cheb_t<16><<<nbt, 256, 0, stream>>>(feat, bufA, bufB, W1, b1, bufC, N);

    // ---- EdgeConv 1
    k_e1_t<<<nbt, 256, 0, stream>>>(bufC, Wt1, Wp1, bt1, bp1, md, bufB, N);
    k_e2_b<<<nbw, 256, 0, stream>>>(md, bufB, row_off, csr, dinv, bufD, hd, N);

    // ---- Cheb layer 2
    k_aggr64<<<nbw, 256, 0, stream>>>(hd, nullptr, dinv, row_off, csr, bufA, xd, -1.f, 0.f, N);
    k_aggr64<<<nbw, 256, 0, stream>>>(xd, bufD, dinv, row_off, csr, bufB, nullptr, -2.f, -1.f, N);
    k_cheb_t<64><<<nbt, 256, 0, stream>>>(bufD, bufA, bufB, W2, b2, bufC, N);

    // ---- EdgeConv 2
    k_e1_t<<<nbt, 256, 0, stream>>>(bufC, Wt2, Wp2, bt2, bp2, md, bufB, N);
    k_e2_b<<<nbw, 256, 0, stream>>>(md, bufB, row_off, csr, dinv, bufD, hd, N);

    // ---- Cheb layer 3
    k_aggr64<<<nbw, 256, 0, stream>>>(hd, nullptr, dinv, row_off, csr, bufA, xd, -1.f, 0.f, N);
    k_aggr64<<<nbw, 256, 0, stream>>>(xd, bufD, dinv, row_off, csr, bufB, nullptr, -2.f, -1.f, N);
    k_cheb_t<64><<<nbt, 256, 0, stream>>>(bufD, bufA, bufB, W3, b3, bufC, N);

    // ---- per-graph mean pooling
    k_pool<<<npool, 256, 0, stream>>>(bufC, gid, out, gcnt, N);
    k_div<<<(out_size + 255) / 256, 256, 0, stream>>>(out, gcnt, out_size);
}

// Round 11
// 665.147 us; speedup vs baseline: 2.1735x; 1.1290x over previous
//
#include <hip/hip_runtime.h>
#include <hip/hip_bf16.h>
#include <math.h>

typedef __attribute__((ext_vector_type(8))) short short8;
typedef __attribute__((ext_vector_type(4))) float floatx4;

__device__ __forceinline__ unsigned short bfb(float x) {
    union { __hip_bfloat16 h; unsigned short u; } c;
    c.h = __float2bfloat16(x);
    return c.u;
}
__device__ __forceinline__ float bf2f(unsigned short u) {
    union { unsigned int i; float f; } c;
    c.i = ((unsigned int)u) << 16;
    return c.f;
}

// ---------------- bucketed CSR build v2 (R10-verified) ----------------

__global__ __launch_bounds__(256) void k_bhist(const int* __restrict__ dst, int* __restrict__ bcnt, int E) {
    __shared__ int h[512];
    int t = threadIdx.x;
    for (int i = t; i < 512; i += 256) h[i] = 0;
    __syncthreads();
    int step = gridDim.x * 256;
    for (int i = blockIdx.x * 256 + t; i < E; i += step) atomicAdd(&h[dst[i] >> 8], 1);
    __syncthreads();
    for (int i = t; i < 512; i += 256) if (h[i]) atomicAdd(&bcnt[i], h[i]);
}

__global__ __launch_bounds__(512) void k_scanBkt(const int* __restrict__ bcnt, int* __restrict__ boff,
                                                 int* __restrict__ bcur, int nb, int E) {
    __shared__ int s[512];
    int t = threadIdx.x;
    int v = (t < nb) ? bcnt[t] : 0;
    s[t] = v;
    __syncthreads();
    for (int off = 1; off < 512; off <<= 1) {
        int x = (t >= off) ? s[t - off] : 0;
        __syncthreads();
        s[t] += x;
        __syncthreads();
    }
    if (t < nb) { boff[t] = s[t] - v; bcur[t] = s[t] - v; }
    if (t == 0) boff[nb] = E;
}

#define PCHUNK 8192

__global__ __launch_bounds__(256) void k_partA(const int* __restrict__ src, const int* __restrict__ dst,
                                               int* __restrict__ bcur, uint2* __restrict__ ebuf, int E) {
    __shared__ int h[512];
    __shared__ int base[512];
    int t = threadIdx.x;
    for (int i = t; i < 512; i += 256) h[i] = 0;
    __syncthreads();
    int start = blockIdx.x * PCHUNK;
    int end = start + PCHUNK < E ? start + PCHUNK : E;
    for (int i = start + t; i < end; i += 256) atomicAdd(&h[dst[i] >> 8], 1);
    __syncthreads();
    for (int i = t; i < 512; i += 256) {
        int c = h[i];
        base[i] = c ? atomicAdd(&bcur[i], c) : 0;
        h[i] = 0;
    }
    __syncthreads();
    for (int i = start + t; i < end; i += 256) {
        int d = dst[i];
        int b = d >> 8;
        int r = atomicAdd(&h[b], 1);
        ebuf[base[b] + r] = make_uint2((unsigned)src[i], (unsigned)d);
    }
}

__global__ __launch_bounds__(256) void k_cnt(const uint2* __restrict__ ebuf, const int* __restrict__ boff,
                                             int* __restrict__ cnt, int N) {
    __shared__ int h[256];
    int b = blockIdx.x, t = threadIdx.x;
    h[t] = 0;
    __syncthreads();
    int beg = boff[b], end = boff[b + 1];
    for (int e = beg + t; e < end; e += 256) atomicAdd(&h[ebuf[e].y & 255], 1);
    __syncthreads();
    int node = (b << 8) + t;
    if (node < N) cnt[node] = h[t];
}

__global__ __launch_bounds__(256) void k_scanA(const int* __restrict__ cnt, int* __restrict__ bsum, int N) {
    __shared__ int s[256];
    int t = threadIdx.x;
    int i = blockIdx.x * 256 + t;
    s[t] = (i < N) ? cnt[i] : 0;
    __syncthreads();
    for (int off = 128; off > 0; off >>= 1) {
        if (t < off) s[t] += s[t + off];
        __syncthreads();
    }
    if (t == 0) bsum[blockIdx.x] = s[0];
}

__global__ __launch_bounds__(512) void k_scanB(int* __restrict__ bsum, int B) {
    __shared__ int s[512];
    int t = threadIdx.x;
    int v = (t < B) ? bsum[t] : 0;
    s[t] = v;
    __syncthreads();
    for (int off = 1; off < 512; off <<= 1) {
        int x = (t >= off) ? s[t - off] : 0;
        __syncthreads();
        s[t] += x;
        __syncthreads();
    }
    if (t < B) bsum[t] = s[t] - v;   // exclusive
}

__global__ __launch_bounds__(256) void k_scanC(const int* __restrict__ cnt, const int* __restrict__ bsum,
                                               int* __restrict__ row_off, float* __restrict__ dinv, int N, int E) {
    __shared__ int s[256];
    int t = threadIdx.x;
    int i = blockIdx.x * 256 + t;
    int v = (i < N) ? cnt[i] : 0;
    s[t] = v;
    __syncthreads();
    for (int off = 1; off < 256; off <<= 1) {
        int x = (t >= off) ? s[t - off] : 0;
        __syncthreads();
        s[t] += x;
        __syncthreads();
    }
    if (i < N) {
        int excl = bsum[blockIdx.x] + s[t] - v;
        row_off[i] = excl;
        dinv[i]    = rsqrtf((float)(v > 1 ? v : 1));
    }
    if (i == 0) row_off[N] = E;
}

__global__ __launch_bounds__(256) void k_scat2(const uint2* __restrict__ ebuf, const int* __restrict__ boff,
                                               const int* __restrict__ row_off, int* __restrict__ csr, int N) {
    __shared__ int cur[256];
    int b = blockIdx.x, t = threadIdx.x;
    int node = (b << 8) + t;
    cur[t] = (node < N) ? row_off[node] : 0;
    __syncthreads();
    int beg = boff[b], end = boff[b + 1];
    for (int e = beg + t; e < end; e += 256) {
        uint2 ed = ebuf[e];
        int pos = atomicAdd(&cur[ed.y & 255], 1);
        csr[pos] = (int)ed.x;
    }
}

// ---------------- feat -> bf16 pre-scaled ----------------

__global__ __launch_bounds__(256) void k_feat16(const float* __restrict__ feat, const float* __restrict__ dinv,
                                                unsigned short* __restrict__ featd, int total) {
    int i = blockIdx.x * 256 + threadIdx.x;
    if (i < total) featd[i] = bfb(feat[i] * dinv[i >> 4]);
}

// ---------------- 16-dim Chebyshev aggregation (bf16 gather) ----------------

__global__ __launch_bounds__(256) void k_aggr16(const unsigned short* __restrict__ Xd, const float* __restrict__ Z,
                                                const float* __restrict__ dinv,
                                                const int* __restrict__ row_off, const int* __restrict__ csr,
                                                float* __restrict__ out, unsigned short* __restrict__ outd,
                                                float alpha, float beta, int N) {
    const int D = 16;
    int t = blockIdx.x * blockDim.x + threadIdx.x;
    int node = t / D;
    int d = t % D;
    if (node >= N) return;
    int beg = row_off[node], end = row_off[node + 1];
    float a0 = 0.f, a1 = 0.f, a2 = 0.f, a3 = 0.f;
    int j = beg;
    for (; j + 3 < end; j += 4) {
        int s0 = csr[j], s1 = csr[j + 1], s2 = csr[j + 2], s3 = csr[j + 3];
        a0 += bf2f(Xd[s0 * D + d]);
        a1 += bf2f(Xd[s1 * D + d]);
        a2 += bf2f(Xd[s2 * D + d]);
        a3 += bf2f(Xd[s3 * D + d]);
    }
    for (; j < end; ++j) a0 += bf2f(Xd[csr[j] * D + d]);
    float acc = (a0 + a1) + (a2 + a3);
    float dn = dinv[node];
    float v = alpha * dn * acc;
    if (Z) v += beta * Z[node * D + d];
    out[node * D + d] = v;
    if (outd) outd[node * D + d] = bfb(v * dn);
}

// ---------------- 64-dim Chebyshev aggregation, 8-wide paired-edge gather (R10) ----------------

__global__ __launch_bounds__(256) void k_aggr64(const unsigned short* __restrict__ Xd, const float* __restrict__ Z,
                                                const float* __restrict__ dinv,
                                                const int* __restrict__ row_off, const int* __restrict__ csr,
                                                float* __restrict__ out, unsigned short* __restrict__ outd,
                                                float alpha, float beta, int N) {
    int node = blockIdx.x * 4 + (threadIdx.x >> 6);
    if (node >= N) return;
    int lane = threadIdx.x & 63;
    int sub = lane >> 5;
    int c2 = (lane & 31) * 2;
    int beg = row_off[node], end = row_off[node + 1];
    float ax = 0.f, ay = 0.f, bx = 0.f, by = 0.f;
    float cx = 0.f, cy = 0.f, dx = 0.f, dy = 0.f;
    int j = beg;
    for (; j + 7 < end; j += 8) {
        int s0 = csr[j + sub];
        int s1 = csr[j + 2 + sub];
        int s2 = csr[j + 4 + sub];
        int s3 = csr[j + 6 + sub];
        ushort2 x0 = *(const ushort2*)&Xd[s0 * 64 + c2];
        ushort2 x1 = *(const ushort2*)&Xd[s1 * 64 + c2];
        ushort2 x2 = *(const ushort2*)&Xd[s2 * 64 + c2];
        ushort2 x3 = *(const ushort2*)&Xd[s3 * 64 + c2];
        ax += bf2f(x0.x); ay += bf2f(x0.y);
        bx += bf2f(x1.x); by += bf2f(x1.y);
        cx += bf2f(x2.x); cy += bf2f(x2.y);
        dx += bf2f(x3.x); dy += bf2f(x3.y);
    }
    for (; j + 3 < end; j += 4) {
        int s0 = csr[j + sub];
        int s1 = csr[j + 2 + sub];
        ushort2 x0 = *(const ushort2*)&Xd[s0 * 64 + c2];
        ushort2 x1 = *(const ushort2*)&Xd[s1 * 64 + c2];
        ax += bf2f(x0.x); ay += bf2f(x0.y);
        bx += bf2f(x1.x); by += bf2f(x1.y);
    }
    for (; j + 1 < end; j += 2) {
        int s0 = csr[j + sub];
        ushort2 x0 = *(const ushort2*)&Xd[s0 * 64 + c2];
        ax += bf2f(x0.x); ay += bf2f(x0.y);
    }
    if (j < end && sub == 0) {
        int s0 = csr[j];
        ushort2 x0 = *(const ushort2*)&Xd[s0 * 64 + c2];
        ax += bf2f(x0.x); ay += bf2f(x0.y);
    }
    float fx = (ax + bx) + (cx + dx);
    float fy = (ay + by) + (cy + dy);
    fx += __shfl_xor(fx, 32);
    fy += __shfl_xor(fy, 32);
    if (sub == 0) {
        float dn = dinv[node];
        float vx = alpha * dn * fx;
        float vy = alpha * dn * fy;
        if (Z) {
            float2 zv = *(const float2*)&Z[(size_t)node * 64 + c2];
            vx += beta * zv.x;
            vy += beta * zv.y;
        }
        float2 r = { vx, vy };
        *(float2*)&out[(size_t)node * 64 + c2] = r;
        if (outd) {
            ushort2 u = { bfb(vx * dn), bfb(vy * dn) };
            *(ushort2*)&outd[(size_t)node * 64 + c2] = u;
        }
    }
}

// ---------------- Cheb matmul via MFMA 16x16x32 bf16 ----------------
// out = relu(b + [X0|X1|X2] @ [W0;W1;W2]). Block = 64 nodes, wave = 16-node strip.
// A/B fragment map: [idx=lane&15][k=(lane>>4)*8+j]; C/D: col=lane&15, row=(lane>>4)*4+reg
// (m89/m120-verified). X,W staged bf16 in LDS; KDIM=16 pads K 48->64 with zeros.
// R10 counters: fp32 version was LDS-issue-bound (35.6 LDS cyc per 32 FMA cyc).

template <int KDIM>
__global__ __launch_bounds__(256) void k_cheb_m(const float* __restrict__ X0, const float* __restrict__ X1,
                                                const float* __restrict__ X2, const float* __restrict__ W,
                                                const float* __restrict__ b, float* __restrict__ out, int N) {
    constexpr int KT = (KDIM == 16) ? 64 : 3 * KDIM;   // padded K in LDS
    constexpr int SX = KT + 8;                         // short stride; *2 bytes % 16 == 0
    __shared__ unsigned short Xs[64 * SX];
    __shared__ unsigned short Ws[64 * SX];
    int t = threadIdx.x;

    // ---- stage X (bf16) : thread covers node t&63, k-span (t>>6)*(KDIM/4)
    {
        int sn = t & 63;
        int gn = blockIdx.x * 64 + sn; if (gn >= N) gn = N - 1;
        int k0 = (t >> 6) * (KDIM / 4);
        const float* Xp[3] = { X0, X1, X2 };
#pragma unroll
        for (int a = 0; a < 3; ++a) {
            const float* X = Xp[a];
#pragma unroll
            for (int i = 0; i < KDIM / 16; ++i) {
                float4 v = *(const float4*)&X[(size_t)gn * KDIM + k0 + 4 * i];
                ushort4 u = { bfb(v.x), bfb(v.y), bfb(v.z), bfb(v.w) };
                *(ushort4*)&Xs[sn * SX + a * KDIM + k0 + 4 * i] = u;
            }
        }
        if (KDIM == 16) {      // zero-pad k in [48,64)
            int kp = 48 + (t >> 6) * 4;
            ushort4 z = { 0, 0, 0, 0 };
            *(ushort4*)&Xs[sn * SX + kp] = z;
        }
    }
    // ---- stage W transposed: Ws[n][a*KDIM + k] = W[a][k][n]
    for (int idx = t; idx < 3 * KDIM * 64; idx += 256) {
        int a = idx / (KDIM * 64);
        int r = idx % (KDIM * 64);
        int k = r >> 6, n = r & 63;
        Ws[n * SX + a * KDIM + k] = bfb(W[idx]);
    }
    if (KDIM == 16) {
        for (int idx = t; idx < 1024; idx += 256) {
            int n = idx & 63, k = 48 + (idx >> 6);
            Ws[n * SX + k] = 0;
        }
    }
    __syncthreads();

    int wave = t >> 6, lane = t & 63;
    int fi = lane & 15, quad = lane >> 4;
    int arow = wave * 16 + fi;

    floatx4 acc0 = {0.f,0.f,0.f,0.f}, acc1 = {0.f,0.f,0.f,0.f}, acc2 = {0.f,0.f,0.f,0.f}, acc3 = {0.f,0.f,0.f,0.f};
#pragma unroll
    for (int ks = 0; ks < KT / 32; ++ks) {
        short8 af = *(const short8*)&Xs[arow * SX + ks * 32 + quad * 8];
        short8 b0 = *(const short8*)&Ws[(0 * 16 + fi) * SX + ks * 32 + quad * 8];
        short8 b1 = *(const short8*)&Ws[(1 * 16 + fi) * SX + ks * 32 + quad * 8];
        short8 b2 = *(const short8*)&Ws[(2 * 16 + fi) * SX + ks * 32 + quad * 8];
        short8 b3 = *(const short8*)&Ws[(3 * 16 + fi) * SX + ks * 32 + quad * 8];
        acc0 = __builtin_amdgcn_mfma_f32_16x16x32_bf16(af, b0, acc0, 0, 0, 0);
        acc1 = __builtin_amdgcn_mfma_f32_16x16x32_bf16(af, b1, acc1, 0, 0, 0);
        acc2 = __builtin_amdgcn_mfma_f32_16x16x32_bf16(af, b2, acc2, 0, 0, 0);
        acc3 = __builtin_amdgcn_mfma_f32_16x16x32_bf16(af, b3, acc3, 0, 0, 0);
    }

    int nbase = blockIdx.x * 64 + wave * 16 + quad * 4;
    floatx4 accs[4] = { acc0, acc1, acc2, acc3 };
#pragma unroll
    for (int nt = 0; nt < 4; ++nt) {
        int col = nt * 16 + fi;
        float bias = b[col];
#pragma unroll
        for (int reg = 0; reg < 4; ++reg) {
            int node = nbase + reg;
            if (node < N) out[(size_t)node * 64 + col] = fmaxf(accs[nt][reg] + bias, 0.f);
        }
    }
}

// ---------------- EdgeConv stage 1 via MFMA: [m|p] = X @ [Wt | Wt+Wp] ----------------

__global__ __launch_bounds__(256) void k_e1_m(const float* __restrict__ X, const float* __restrict__ Wt,
                                              const float* __restrict__ Wp, const float* __restrict__ bt,
                                              const float* __restrict__ bp,
                                              unsigned short* __restrict__ md, float* __restrict__ pbuf, int N) {
    constexpr int SX = 72;
    __shared__ unsigned short Xs[64 * SX];
    __shared__ unsigned short Ws[128 * SX];
    int t = threadIdx.x;

    {
        int sn = t & 63;
        int gn = blockIdx.x * 64 + sn; if (gn >= N) gn = N - 1;
        int k0 = (t >> 6) * 16;
#pragma unroll
        for (int i = 0; i < 4; ++i) {
            float4 v = *(const float4*)&X[(size_t)gn * 64 + k0 + 4 * i];
            ushort4 u = { bfb(v.x), bfb(v.y), bfb(v.z), bfb(v.w) };
            *(ushort4*)&Xs[sn * SX + k0 + 4 * i] = u;
        }
    }
    for (int idx = t; idx < 4096; idx += 256) {
        int k = idx >> 6, n = idx & 63;
        float wt = Wt[idx];
        Ws[n * SX + k] = bfb(wt);
        Ws[(64 + n) * SX + k] = bfb(wt + Wp[idx]);
    }
    __syncthreads();

    int wave = t >> 6, lane = t & 63;
    int fi = lane & 15, quad = lane >> 4;
    int arow = wave * 16 + fi;

    floatx4 acc[8];
#pragma unroll
    for (int i = 0; i < 8; ++i) acc[i] = (floatx4){0.f,0.f,0.f,0.f};
#pragma unroll
    for (int ks = 0; ks < 2; ++ks) {
        short8 af = *(const short8*)&Xs[arow * SX + ks * 32 + quad * 8];
#pragma unroll
        for (int nt = 0; nt < 8; ++nt) {
            short8 bf = *(const short8*)&Ws[(nt * 16 + fi) * SX + ks * 32 + quad * 8];
            acc[nt] = __builtin_amdgcn_mfma_f32_16x16x32_bf16(af, bf, acc[nt], 0, 0, 0);
        }
    }

    int nbase = blockIdx.x * 64 + wave * 16 + quad * 4;
#pragma unroll
    for (int nt = 0; nt < 8; ++nt) {
        int col = nt * 16 + fi;
        if (col < 64) {
#pragma unroll
            for (int reg = 0; reg < 4; ++reg) {
                int node = nbase + reg;
                if (node < N) md[(size_t)node * 64 + col] = bfb(acc[nt][reg]);
            }
        } else {
            int cc = col - 64;
            float bias = bt[cc] + bp[cc];
#pragma unroll
            for (int reg = 0; reg < 4; ++reg) {
                int node = nbase + reg;
                if (node < N) pbuf[(size_t)node * 64 + cc] = acc[nt][reg] + bias;
            }
        }
    }
}

// ---------------- EdgeConv stage 2, 8-wide paired-edge bf16 gather (R10) ----------------

__global__ __launch_bounds__(256) void k_e2_b(const unsigned short* __restrict__ md, const float* __restrict__ pbuf,
                                              const int* __restrict__ row_off, const int* __restrict__ csr,
                                              const float* __restrict__ dinv, float* __restrict__ out,
                                              unsigned short* __restrict__ outd, int N) {
    int node = blockIdx.x * 4 + (threadIdx.x >> 6);
    if (node >= N) return;
    int lane = threadIdx.x & 63;
    int sub = lane >> 5;
    int c2 = (lane & 31) * 2;
    int beg = row_off[node], end = row_off[node + 1];
    float ax = -INFINITY, ay = -INFINITY, bx = -INFINITY, by = -INFINITY;
    float cx = -INFINITY, cy = -INFINITY, dx = -INFINITY, dy = -INFINITY;
    int j = beg;
    for (; j + 7 < end; j += 8) {
        int s0 = csr[j + sub];
        int s1 = csr[j + 2 + sub];
        int s2 = csr[j + 4 + sub];
        int s3 = csr[j + 6 + sub];
        ushort2 x0 = *(const ushort2*)&md[s0 * 64 + c2];
        ushort2 x1 = *(const ushort2*)&md[s1 * 64 + c2];
        ushort2 x2 = *(const ushort2*)&md[s2 * 64 + c2];
        ushort2 x3 = *(const ushort2*)&md[s3 * 64 + c2];
        ax = fmaxf(ax, -bf2f(x0.x)); ay = fmaxf(ay, -bf2f(x0.y));
        bx = fmaxf(bx, -bf2f(x1.x)); by = fmaxf(by, -bf2f(x1.y));
        cx = fmaxf(cx, -bf2f(x2.x)); cy = fmaxf(cy, -bf2f(x2.y));
        dx = fmaxf(dx, -bf2f(x3.x)); dy = fmaxf(dy, -bf2f(x3.y));
    }
    for (; j + 3 < end; j += 4) {
        int s0 = csr[j + sub];
        int s1 = csr[j + 2 + sub];
        ushort2 x0 = *(const ushort2*)&md[s0 * 64 + c2];
        ushort2 x1 = *(const ushort2*)&md[s1 * 64 + c2];
        ax = fmaxf(ax, -bf2f(x0.x)); ay = fmaxf(ay, -bf2f(x0.y));
        bx = fmaxf(bx, -bf2f(x1.x)); by = fmaxf(by, -bf2f(x1.y));
    }
    for (; j + 1 < end; j += 2) {
        int s0 = csr[j + sub];
        ushort2 x0 = *(const ushort2*)&md[s0 * 64 + c2];
        ax = fmaxf(ax, -bf2f(x0.x)); ay = fmaxf(ay, -bf2f(x0.y));
    }
    if (j < end && sub == 0) {
        int s0 = csr[j];
        ushort2 x0 = *(const ushort2*)&md[s0 * 64 + c2];
        ax = fmaxf(ax, -bf2f(x0.x)); ay = fmaxf(ay, -bf2f(x0.y));
    }
    float fx = fmaxf(fmaxf(ax, bx), fmaxf(cx, dx));
    float fy = fmaxf(fmaxf(ay, by), fmaxf(cy, dy));
    fx = fmaxf(fx, __shfl_xor(fx, 32));
    fy = fmaxf(fy, __shfl_xor(fy, 32));
    if (sub == 0) {
        float rx = 0.f, ry = 0.f;
        if (end > beg) {
            float2 pv = *(const float2*)&pbuf[(size_t)node * 64 + c2];
            rx = fmaxf(pv.x + fx, 0.f);
            ry = fmaxf(pv.y + fy, 0.f);
        }
        float2 r = { rx, ry };
        *(float2*)&out[(size_t)node * 64 + c2] = r;
        float dn = dinv[node];
        ushort2 u = { bfb(rx * dn), bfb(ry * dn) };
        *(ushort2*)&outd[(size_t)node * 64 + c2] = u;
    }
}

// ---------------- graph mean pooling (segmented: gid is sorted) ----------------

__global__ __launch_bounds__(256) void k_pool(const float* __restrict__ h, const int* __restrict__ gid,
                                              float* __restrict__ out, float* __restrict__ gcnt, int N) {
    const int CHUNK = 128;
    int wave = blockIdx.x * 4 + (threadIdx.x >> 6);
    int lane = threadIdx.x & 63;
    int beg = wave * CHUNK;
    if (beg >= N) return;
    int end = beg + CHUNK < N ? beg + CHUNK : N;
    int gcur = gid[beg];
    float acc = 0.f;
    int cnt = 0;
    for (int n = beg; n < end; ++n) {
        int g = gid[n];
        float v = h[n * 64 + lane];
        if (g != gcur) {
            atomicAdd(&out[gcur * 64 + lane], acc);
            if (lane == 0) atomicAdd(&gcnt[gcur], (float)cnt);
            gcur = g; acc = 0.f; cnt = 0;
        }
        acc += v;
        ++cnt;
    }
    atomicAdd(&out[gcur * 64 + lane], acc);
    if (lane == 0) atomicAdd(&gcnt[gcur], (float)cnt);
}

__global__ __launch_bounds__(256) void k_div(float* __restrict__ out, const float* __restrict__ gcnt, int total) {
    int i = blockIdx.x * blockDim.x + threadIdx.x;
    if (i < total) out[i] /= fmaxf(gcnt[i >> 6], 1.f);
}

// ---------------- launcher ----------------

extern "C" void kernel_launch(void* const* d_in, const int* in_sizes, int n_in,
                              void* d_out, int out_size, void* d_ws, size_t ws_size,
                              hipStream_t stream) {
    const float* feat = (const float*)d_in[0];
    const int* src = (const int*)d_in[1];
    const int* dst = (const int*)d_in[2];
    const int* gid = (const int*)d_in[3];
    const float* W1 = (const float*)d_in[4];  const float* b1 = (const float*)d_in[5];
    const float* W2 = (const float*)d_in[6];  const float* b2 = (const float*)d_in[7];
    const float* W3 = (const float*)d_in[8];  const float* b3 = (const float*)d_in[9];
    const float* Wt1 = (const float*)d_in[10]; const float* bt1 = (const float*)d_in[11];
    const float* Wp1 = (const float*)d_in[12]; const float* bp1 = (const float*)d_in[13];
    const float* Wt2 = (const float*)d_in[14]; const float* bt2 = (const float*)d_in[15];
    const float* Wp2 = (const float*)d_in[16]; const float* bp2 = (const float*)d_in[17];
    float* out = (float*)d_out;

    const int N = in_sizes[0] / 16;
    const int E = in_sizes[1];
    const int G = out_size / 64;
    const int nb = (N + 255) >> 8;      // buckets (<= 512)

    char* p = (char*)d_ws;
    auto alloc = [&](size_t nbytes) {
        void* r = (void*)p;
        p += (nbytes + 255) & ~(size_t)255;
        return r;
    };
    int* cnt      = (int*)alloc((size_t)N * 4);
    int* row_off  = (int*)alloc((size_t)(N + 1) * 4);
    int* csr      = (int*)alloc((size_t)E * 4);
    int* bsum     = (int*)alloc(512 * 4);
    int* bcnt     = (int*)alloc(512 * 4);
    int* boff     = (int*)alloc(513 * 4);
    int* bcur     = (int*)alloc(512 * 4);
    float* dinv   = (float*)alloc((size_t)N * 4);
    float* bufA   = (float*)alloc((size_t)N * 64 * 4);
    float* bufB   = (float*)alloc((size_t)N * 64 * 4);
    float* bufC   = (float*)alloc((size_t)N * 64 * 4);
    float* bufD   = (float*)alloc((size_t)N * 64 * 4);
    unsigned short* md = (unsigned short*)alloc((size_t)N * 64 * 2);
    float* gcnt   = (float*)alloc((size_t)G * 4);

    uint2* ebuf = (uint2*)bufA;   // alias: bufA dead until after CSR build
    unsigned short* hd = (unsigned short*)bufC;                    // bf16 scratch in bufC dead windows
    unsigned short* xd = (unsigned short*)bufC + (size_t)N * 64;

    hipMemsetAsync(bcnt, 0, 512 * 4, stream);
    hipMemsetAsync(gcnt, 0, (size_t)G * 4, stream);
    hipMemsetAsync(d_out, 0, (size_t)out_size * 4, stream);

    const int B = (N + 255) / 256;
    const int nb16 = (N * 16 + 255) / 256;
    const int nbw = (N + 3) / 4;
    const int npool = ((N + 127) / 128 + 3) / 4;
    const int nbt = (N + 63) / 64;
    const int npart = (E + PCHUNK - 1) / PCHUNK;

    // ---- bucketed CSR build v2
    k_bhist<<<256, 256, 0, stream>>>(dst, bcnt, E);
    k_scanBkt<<<1, 512, 0, stream>>>(bcnt, boff, bcur, nb, E);
    k_partA<<<npart, 256, 0, stream>>>(src, dst, bcur, ebuf, E);
    k_cnt<<<nb, 256, 0, stream>>>(ebuf, boff, cnt, N);
    k_scanA<<<B, 256, 0, stream>>>(cnt, bsum, N);
    k_scanB<<<1, 512, 0, stream>>>(bsum, B);
    k_scanC<<<B, 256, 0, stream>>>(cnt, bsum, row_off, dinv, N, E);
    k_scat2<<<nb, 256, 0, stream>>>(ebuf, boff, row_off, csr, N);

    // ---- Cheb layer 1 (IN=16)
    k_feat16<<<nb16, 256, 0, stream>>>(feat, dinv, hd, N * 16);
    k_aggr16<<<nb16, 256, 0, stream>>>(hd, nullptr, dinv, row_off, csr, bufA, xd, -1.f, 0.f, N);
    k_aggr16<<<nb16, 256, 0, stream>>>(xd, feat, dinv, row_off, csr, bufB, nullptr, -2.f, -1.f, N);
    k_cheb_m<16><<<nbt, 256, 0, stream>>>(feat, bufA, bufB, W1, b1, bufC, N);

    // ---- EdgeConv 1
    k_e1_m<<<nbt, 256, 0, stream>>>(bufC, Wt1, Wp1, bt1, bp1, md, bufB, N);
    k_e2_b<<<nbw, 256, 0, stream>>>(md, bufB, row_off, csr, dinv, bufD, hd, N);

    // ---- Cheb layer 2
    k_aggr64<<<nbw, 256, 0, stream>>>(hd, nullptr, dinv, row_off, csr, bufA, xd, -1.f, 0.f, N);
    k_aggr64<<<nbw, 256, 0, stream>>>(xd, bufD, dinv, row_off, csr, bufB, nullptr, -2.f, -1.f, N);
    k_cheb_m<64><<<nbt, 256, 0, stream>>>(bufD, bufA, bufB, W2, b2, bufC, N);

    // ---- EdgeConv 2
    k_e1_m<<<nbt, 256, 0, stream>>>(bufC, Wt2, Wp2, bt2, bp2, md, bufB, N);
    k_e2_b<<<nbw, 256, 0, stream>>>(md, bufB, row_off, csr, dinv, bufD, hd, N);

    // ---- Cheb layer 3
    k_aggr64<<<nbw, 256, 0, stream>>>(hd, nullptr, dinv, row_off, csr, bufA, xd, -1.f, 0.f, N);
    k_aggr64<<<nbw, 256, 0, stream>>>(xd, bufD, dinv, row_off, csr, bufB, nullptr, -2.f, -1.f, N);
    k_cheb_m<64><<<nbt, 256, 0, stream>>>(bufD, bufA, bufB, W3, b3, bufC, N);

    // ---- per-graph mean pooling
    k_pool<<<npool, 256, 0, stream>>>(bufC, gid, out, gcnt, N);
    k_div<<<(out_size + 255) / 256, 256, 0, stream>>>(out, gcnt, out_size);
}

// Round 12
// 660.338 us; speedup vs baseline: 2.1894x; 1.0073x over previous
//
#include <hip/hip_runtime.h>
#include <hip/hip_bf16.h>
#include <math.h>

typedef __attribute__((ext_vector_type(8))) short short8;
typedef __attribute__((ext_vector_type(4))) float floatx4;

__device__ __forceinline__ unsigned short bfb(float x) {
    union { __hip_bfloat16 h; unsigned short u; } c;
    c.h = __float2bfloat16(x);
    return c.u;
}
__device__ __forceinline__ float bf2f(unsigned short u) {
    union { unsigned int i; float f; } c;
    c.i = ((unsigned int)u) << 16;
    return c.f;
}

// ---------------- bucketed CSR build v2 (R10-verified) + packed ebuf ----------------
// ebuf entry = (src<<8) | (dst&255): src<2^17 so fits uint32; halves ebuf traffic.

__global__ __launch_bounds__(256) void k_bhist(const int* __restrict__ dst, int* __restrict__ bcnt, int E) {
    __shared__ int h[512];
    int t = threadIdx.x;
    for (int i = t; i < 512; i += 256) h[i] = 0;
    __syncthreads();
    int step = gridDim.x * 256;
    for (int i = blockIdx.x * 256 + t; i < E; i += step) atomicAdd(&h[dst[i] >> 8], 1);
    __syncthreads();
    for (int i = t; i < 512; i += 256) if (h[i]) atomicAdd(&bcnt[i], h[i]);
}

__global__ __launch_bounds__(512) void k_scanBkt(const int* __restrict__ bcnt, int* __restrict__ boff,
                                                 int* __restrict__ bcur, int nb, int E) {
    __shared__ int s[512];
    int t = threadIdx.x;
    int v = (t < nb) ? bcnt[t] : 0;
    s[t] = v;
    __syncthreads();
    for (int off = 1; off < 512; off <<= 1) {
        int x = (t >= off) ? s[t - off] : 0;
        __syncthreads();
        s[t] += x;
        __syncthreads();
    }
    if (t < nb) { boff[t] = s[t] - v; bcur[t] = s[t] - v; }
    if (t == 0) boff[nb] = E;
}

#define PCHUNK 8192

__global__ __launch_bounds__(256) void k_partA(const int* __restrict__ src, const int* __restrict__ dst,
                                               int* __restrict__ bcur, unsigned* __restrict__ ebuf, int E) {
    __shared__ int h[512];
    __shared__ int base[512];
    int t = threadIdx.x;
    for (int i = t; i < 512; i += 256) h[i] = 0;
    __syncthreads();
    int start = blockIdx.x * PCHUNK;
    int end = start + PCHUNK < E ? start + PCHUNK : E;
    for (int i = start + t; i < end; i += 256) atomicAdd(&h[dst[i] >> 8], 1);
    __syncthreads();
    for (int i = t; i < 512; i += 256) {
        int c = h[i];
        base[i] = c ? atomicAdd(&bcur[i], c) : 0;
        h[i] = 0;
    }
    __syncthreads();
    for (int i = start + t; i < end; i += 256) {
        int d = dst[i];
        int b = d >> 8;
        int r = atomicAdd(&h[b], 1);
        ebuf[base[b] + r] = ((unsigned)src[i] << 8) | (unsigned)(d & 255);
    }
}

__global__ __launch_bounds__(256) void k_cnt(const unsigned* __restrict__ ebuf, const int* __restrict__ boff,
                                             int* __restrict__ cnt, int N) {
    __shared__ int h[256];
    int b = blockIdx.x, t = threadIdx.x;
    h[t] = 0;
    __syncthreads();
    int beg = boff[b], end = boff[b + 1];
    for (int e = beg + t; e < end; e += 256) atomicAdd(&h[ebuf[e] & 255], 1);
    __syncthreads();
    int node = (b << 8) + t;
    if (node < N) cnt[node] = h[t];
}

__global__ __launch_bounds__(256) void k_scanA(const int* __restrict__ cnt, int* __restrict__ bsum, int N) {
    __shared__ int s[256];
    int t = threadIdx.x;
    int i = blockIdx.x * 256 + t;
    s[t] = (i < N) ? cnt[i] : 0;
    __syncthreads();
    for (int off = 128; off > 0; off >>= 1) {
        if (t < off) s[t] += s[t + off];
        __syncthreads();
    }
    if (t == 0) bsum[blockIdx.x] = s[0];
}

__global__ __launch_bounds__(512) void k_scanB(int* __restrict__ bsum, int B) {
    __shared__ int s[512];
    int t = threadIdx.x;
    int v = (t < B) ? bsum[t] : 0;
    s[t] = v;
    __syncthreads();
    for (int off = 1; off < 512; off <<= 1) {
        int x = (t >= off) ? s[t - off] : 0;
        __syncthreads();
        s[t] += x;
        __syncthreads();
    }
    if (t < B) bsum[t] = s[t] - v;   // exclusive
}

__global__ __launch_bounds__(256) void k_scanC(const int* __restrict__ cnt, const int* __restrict__ bsum,
                                               int* __restrict__ row_off, float* __restrict__ dinv, int N, int E) {
    __shared__ int s[256];
    int t = threadIdx.x;
    int i = blockIdx.x * 256 + t;
    int v = (i < N) ? cnt[i] : 0;
    s[t] = v;
    __syncthreads();
    for (int off = 1; off < 256; off <<= 1) {
        int x = (t >= off) ? s[t - off] : 0;
        __syncthreads();
        s[t] += x;
        __syncthreads();
    }
    if (i < N) {
        int excl = bsum[blockIdx.x] + s[t] - v;
        row_off[i] = excl;
        dinv[i]    = rsqrtf((float)(v > 1 ? v : 1));
    }
    if (i == 0) row_off[N] = E;
}

__global__ __launch_bounds__(256) void k_scat2(const unsigned* __restrict__ ebuf, const int* __restrict__ boff,
                                               const int* __restrict__ row_off, int* __restrict__ csr, int N) {
    __shared__ int cur[256];
    int b = blockIdx.x, t = threadIdx.x;
    int node = (b << 8) + t;
    cur[t] = (node < N) ? row_off[node] : 0;
    __syncthreads();
    int beg = boff[b], end = boff[b + 1];
    for (int e = beg + t; e < end; e += 256) {
        unsigned ed = ebuf[e];
        int pos = atomicAdd(&cur[ed & 255], 1);
        csr[pos] = (int)(ed >> 8);
    }
}

// ---------------- feat -> bf16 pre-scaled ----------------

__global__ __launch_bounds__(256) void k_feat16(const float* __restrict__ feat, const float* __restrict__ dinv,
                                                unsigned short* __restrict__ featd, int total) {
    int i = blockIdx.x * 256 + threadIdx.x;
    if (i < total) featd[i] = bfb(feat[i] * dinv[i >> 4]);
}

// ---------------- 16-dim Chebyshev aggregation (bf16 gather) ----------------

__global__ __launch_bounds__(256) void k_aggr16(const unsigned short* __restrict__ Xd, const float* __restrict__ Z,
                                                const float* __restrict__ dinv,
                                                const int* __restrict__ row_off, const int* __restrict__ csr,
                                                float* __restrict__ out, unsigned short* __restrict__ outd,
                                                float alpha, float beta, int N) {
    const int D = 16;
    int t = blockIdx.x * blockDim.x + threadIdx.x;
    int node = t / D;
    int d = t % D;
    if (node >= N) return;
    int beg = row_off[node], end = row_off[node + 1];
    float a0 = 0.f, a1 = 0.f, a2 = 0.f, a3 = 0.f;
    int j = beg;
    for (; j + 3 < end; j += 4) {
        int s0 = csr[j], s1 = csr[j + 1], s2 = csr[j + 2], s3 = csr[j + 3];
        a0 += bf2f(Xd[s0 * D + d]);
        a1 += bf2f(Xd[s1 * D + d]);
        a2 += bf2f(Xd[s2 * D + d]);
        a3 += bf2f(Xd[s3 * D + d]);
    }
    for (; j < end; ++j) a0 += bf2f(Xd[csr[j] * D + d]);
    float acc = (a0 + a1) + (a2 + a3);
    float dn = dinv[node];
    float v = alpha * dn * acc;
    if (Z) v += beta * Z[node * D + d];
    out[node * D + d] = v;
    if (outd) outd[node * D + d] = bfb(v * dn);
}

// ---------------- 64-dim Chebyshev aggregation, QUAD-EDGE gather ----------------
// Wave = node. 4 groups of 16 lanes; each group handles one edge, lane loads ushort4
// (4 dims). One vmem instruction covers 4 edges (vs 2 in R10). Cross-group reduce via
// shfl_xor(16/32); lanes 0-15 write float4 + ushort4.

__global__ __launch_bounds__(256) void k_aggr64(const unsigned short* __restrict__ Xd, const float* __restrict__ Z,
                                                const float* __restrict__ dinv,
                                                const int* __restrict__ row_off, const int* __restrict__ csr,
                                                float* __restrict__ out, unsigned short* __restrict__ outd,
                                                float alpha, float beta, int N) {
    int node = blockIdx.x * 4 + (threadIdx.x >> 6);
    if (node >= N) return;
    int lane = threadIdx.x & 63;
    int g = lane >> 4;
    int c4 = (lane & 15) * 4;
    int beg = row_off[node], end = row_off[node + 1];
    float a0 = 0.f, a1 = 0.f, a2 = 0.f, a3 = 0.f;
    float b0 = 0.f, b1 = 0.f, b2 = 0.f, b3 = 0.f;
    int j = beg;
    for (; j + 7 < end; j += 8) {
        int sA = csr[j + g];
        int sB = csr[j + 4 + g];
        ushort4 xA = *(const ushort4*)&Xd[sA * 64 + c4];
        ushort4 xB = *(const ushort4*)&Xd[sB * 64 + c4];
        a0 += bf2f(xA.x); a1 += bf2f(xA.y); a2 += bf2f(xA.z); a3 += bf2f(xA.w);
        b0 += bf2f(xB.x); b1 += bf2f(xB.y); b2 += bf2f(xB.z); b3 += bf2f(xB.w);
    }
    for (; j < end; j += 4) {
        int idx = j + g;
        int s = csr[idx < end ? idx : end - 1];
        ushort4 x = *(const ushort4*)&Xd[s * 64 + c4];
        if (idx < end) {
            a0 += bf2f(x.x); a1 += bf2f(x.y); a2 += bf2f(x.z); a3 += bf2f(x.w);
        }
    }
    a0 += b0; a1 += b1; a2 += b2; a3 += b3;
    a0 += __shfl_xor(a0, 16); a0 += __shfl_xor(a0, 32);
    a1 += __shfl_xor(a1, 16); a1 += __shfl_xor(a1, 32);
    a2 += __shfl_xor(a2, 16); a2 += __shfl_xor(a2, 32);
    a3 += __shfl_xor(a3, 16); a3 += __shfl_xor(a3, 32);
    if (g == 0) {
        float dn = dinv[node];
        float v0 = alpha * dn * a0;
        float v1 = alpha * dn * a1;
        float v2 = alpha * dn * a2;
        float v3 = alpha * dn * a3;
        if (Z) {
            float4 zv = *(const float4*)&Z[(size_t)node * 64 + c4];
            v0 += beta * zv.x; v1 += beta * zv.y; v2 += beta * zv.z; v3 += beta * zv.w;
        }
        float4 r = { v0, v1, v2, v3 };
        *(float4*)&out[(size_t)node * 64 + c4] = r;
        if (outd) {
            ushort4 u = { bfb(v0 * dn), bfb(v1 * dn), bfb(v2 * dn), bfb(v3 * dn) };
            *(ushort4*)&outd[(size_t)node * 64 + c4] = u;
        }
    }
}

// ---------------- Cheb matmul via MFMA 16x16x32 bf16 (R11-verified) ----------------

template <int KDIM>
__global__ __launch_bounds__(256) void k_cheb_m(const float* __restrict__ X0, const float* __restrict__ X1,
                                                const float* __restrict__ X2, const float* __restrict__ W,
                                                const float* __restrict__ b, float* __restrict__ out, int N) {
    constexpr int KT = (KDIM == 16) ? 64 : 3 * KDIM;
    constexpr int SX = KT + 8;
    __shared__ unsigned short Xs[64 * SX];
    __shared__ unsigned short Ws[64 * SX];
    int t = threadIdx.x;

    {
        int sn = t & 63;
        int gn = blockIdx.x * 64 + sn; if (gn >= N) gn = N - 1;
        int k0 = (t >> 6) * (KDIM / 4);
        const float* Xp[3] = { X0, X1, X2 };
#pragma unroll
        for (int a = 0; a < 3; ++a) {
            const float* X = Xp[a];
#pragma unroll
            for (int i = 0; i < KDIM / 16; ++i) {
                float4 v = *(const float4*)&X[(size_t)gn * KDIM + k0 + 4 * i];
                ushort4 u = { bfb(v.x), bfb(v.y), bfb(v.z), bfb(v.w) };
                *(ushort4*)&Xs[sn * SX + a * KDIM + k0 + 4 * i] = u;
            }
        }
        if (KDIM == 16) {
            int kp = 48 + (t >> 6) * 4;
            ushort4 z = { 0, 0, 0, 0 };
            *(ushort4*)&Xs[sn * SX + kp] = z;
        }
    }
    for (int idx = t; idx < 3 * KDIM * 64; idx += 256) {
        int a = idx / (KDIM * 64);
        int r = idx % (KDIM * 64);
        int k = r >> 6, n = r & 63;
        Ws[n * SX + a * KDIM + k] = bfb(W[idx]);
    }
    if (KDIM == 16) {
        for (int idx = t; idx < 1024; idx += 256) {
            int n = idx & 63, k = 48 + (idx >> 6);
            Ws[n * SX + k] = 0;
        }
    }
    __syncthreads();

    int wave = t >> 6, lane = t & 63;
    int fi = lane & 15, quad = lane >> 4;
    int arow = wave * 16 + fi;

    floatx4 acc0 = {0.f,0.f,0.f,0.f}, acc1 = {0.f,0.f,0.f,0.f}, acc2 = {0.f,0.f,0.f,0.f}, acc3 = {0.f,0.f,0.f,0.f};
#pragma unroll
    for (int ks = 0; ks < KT / 32; ++ks) {
        short8 af = *(const short8*)&Xs[arow * SX + ks * 32 + quad * 8];
        short8 b0 = *(const short8*)&Ws[(0 * 16 + fi) * SX + ks * 32 + quad * 8];
        short8 b1 = *(const short8*)&Ws[(1 * 16 + fi) * SX + ks * 32 + quad * 8];
        short8 b2 = *(const short8*)&Ws[(2 * 16 + fi) * SX + ks * 32 + quad * 8];
        short8 b3 = *(const short8*)&Ws[(3 * 16 + fi) * SX + ks * 32 + quad * 8];
        acc0 = __builtin_amdgcn_mfma_f32_16x16x32_bf16(af, b0, acc0, 0, 0, 0);
        acc1 = __builtin_amdgcn_mfma_f32_16x16x32_bf16(af, b1, acc1, 0, 0, 0);
        acc2 = __builtin_amdgcn_mfma_f32_16x16x32_bf16(af, b2, acc2, 0, 0, 0);
        acc3 = __builtin_amdgcn_mfma_f32_16x16x32_bf16(af, b3, acc3, 0, 0, 0);
    }

    int nbase = blockIdx.x * 64 + wave * 16 + quad * 4;
    floatx4 accs[4] = { acc0, acc1, acc2, acc3 };
#pragma unroll
    for (int nt = 0; nt < 4; ++nt) {
        int col = nt * 16 + fi;
        float bias = b[col];
#pragma unroll
        for (int reg = 0; reg < 4; ++reg) {
            int node = nbase + reg;
            if (node < N) out[(size_t)node * 64 + col] = fmaxf(accs[nt][reg] + bias, 0.f);
        }
    }
}

// ---------------- EdgeConv stage 1 via MFMA: [m|p] = X @ [Wt | Wt+Wp] (R11) ----------------

__global__ __launch_bounds__(256) void k_e1_m(const float* __restrict__ X, const float* __restrict__ Wt,
                                              const float* __restrict__ Wp, const float* __restrict__ bt,
                                              const float* __restrict__ bp,
                                              unsigned short* __restrict__ md, float* __restrict__ pbuf, int N) {
    constexpr int SX = 72;
    __shared__ unsigned short Xs[64 * SX];
    __shared__ unsigned short Ws[128 * SX];
    int t = threadIdx.x;

    {
        int sn = t & 63;
        int gn = blockIdx.x * 64 + sn; if (gn >= N) gn = N - 1;
        int k0 = (t >> 6) * 16;
#pragma unroll
        for (int i = 0; i < 4; ++i) {
            float4 v = *(const float4*)&X[(size_t)gn * 64 + k0 + 4 * i];
            ushort4 u = { bfb(v.x), bfb(v.y), bfb(v.z), bfb(v.w) };
            *(ushort4*)&Xs[sn * SX + k0 + 4 * i] = u;
        }
    }
    for (int idx = t; idx < 4096; idx += 256) {
        int k = idx >> 6, n = idx & 63;
        float wt = Wt[idx];
        Ws[n * SX + k] = bfb(wt);
        Ws[(64 + n) * SX + k] = bfb(wt + Wp[idx]);
    }
    __syncthreads();

    int wave = t >> 6, lane = t & 63;
    int fi = lane & 15, quad = lane >> 4;
    int arow = wave * 16 + fi;

    floatx4 acc[8];
#pragma unroll
    for (int i = 0; i < 8; ++i) acc[i] = (floatx4){0.f,0.f,0.f,0.f};
#pragma unroll
    for (int ks = 0; ks < 2; ++ks) {
        short8 af = *(const short8*)&Xs[arow * SX + ks * 32 + quad * 8];
#pragma unroll
        for (int nt = 0; nt < 8; ++nt) {
            short8 bf = *(const short8*)&Ws[(nt * 16 + fi) * SX + ks * 32 + quad * 8];
            acc[nt] = __builtin_amdgcn_mfma_f32_16x16x32_bf16(af, bf, acc[nt], 0, 0, 0);
        }
    }

    int nbase = blockIdx.x * 64 + wave * 16 + quad * 4;
#pragma unroll
    for (int nt = 0; nt < 8; ++nt) {
        int col = nt * 16 + fi;
        if (col < 64) {
#pragma unroll
            for (int reg = 0; reg < 4; ++reg) {
                int node = nbase + reg;
                if (node < N) md[(size_t)node * 64 + col] = bfb(acc[nt][reg]);
            }
        } else {
            int cc = col - 64;
            float bias = bt[cc] + bp[cc];
#pragma unroll
            for (int reg = 0; reg < 4; ++reg) {
                int node = nbase + reg;
                if (node < N) pbuf[(size_t)node * 64 + cc] = acc[nt][reg] + bias;
            }
        }
    }
}

// ---------------- EdgeConv stage 2, QUAD-EDGE bf16 gather ----------------

__global__ __launch_bounds__(256) void k_e2_b(const unsigned short* __restrict__ md, const float* __restrict__ pbuf,
                                              const int* __restrict__ row_off, const int* __restrict__ csr,
                                              const float* __restrict__ dinv, float* __restrict__ out,
                                              unsigned short* __restrict__ outd, int N) {
    int node = blockIdx.x * 4 + (threadIdx.x >> 6);
    if (node >= N) return;
    int lane = threadIdx.x & 63;
    int g = lane >> 4;
    int c4 = (lane & 15) * 4;
    int beg = row_off[node], end = row_off[node + 1];
    float a0 = -INFINITY, a1 = -INFINITY, a2 = -INFINITY, a3 = -INFINITY;
    float b0 = -INFINITY, b1 = -INFINITY, b2 = -INFINITY, b3 = -INFINITY;
    int j = beg;
    for (; j + 7 < end; j += 8) {
        int sA = csr[j + g];
        int sB = csr[j + 4 + g];
        ushort4 xA = *(const ushort4*)&md[sA * 64 + c4];
        ushort4 xB = *(const ushort4*)&md[sB * 64 + c4];
        a0 = fmaxf(a0, -bf2f(xA.x)); a1 = fmaxf(a1, -bf2f(xA.y));
        a2 = fmaxf(a2, -bf2f(xA.z)); a3 = fmaxf(a3, -bf2f(xA.w));
        b0 = fmaxf(b0, -bf2f(xB.x)); b1 = fmaxf(b1, -bf2f(xB.y));
        b2 = fmaxf(b2, -bf2f(xB.z)); b3 = fmaxf(b3, -bf2f(xB.w));
    }
    for (; j < end; j += 4) {
        int idx = j + g;
        int s = csr[idx < end ? idx : end - 1];
        ushort4 x = *(const ushort4*)&md[s * 64 + c4];
        if (idx < end) {
            a0 = fmaxf(a0, -bf2f(x.x)); a1 = fmaxf(a1, -bf2f(x.y));
            a2 = fmaxf(a2, -bf2f(x.z)); a3 = fmaxf(a3, -bf2f(x.w));
        }
    }
    a0 = fmaxf(a0, b0); a1 = fmaxf(a1, b1); a2 = fmaxf(a2, b2); a3 = fmaxf(a3, b3);
    a0 = fmaxf(a0, __shfl_xor(a0, 16)); a0 = fmaxf(a0, __shfl_xor(a0, 32));
    a1 = fmaxf(a1, __shfl_xor(a1, 16)); a1 = fmaxf(a1, __shfl_xor(a1, 32));
    a2 = fmaxf(a2, __shfl_xor(a2, 16)); a2 = fmaxf(a2, __shfl_xor(a2, 32));
    a3 = fmaxf(a3, __shfl_xor(a3, 16)); a3 = fmaxf(a3, __shfl_xor(a3, 32));
    if (g == 0) {
        float r0 = 0.f, r1 = 0.f, r2 = 0.f, r3 = 0.f;
        if (end > beg) {
            float4 pv = *(const float4*)&pbuf[(size_t)node * 64 + c4];
            r0 = fmaxf(pv.x + a0, 0.f);
            r1 = fmaxf(pv.y + a1, 0.f);
            r2 = fmaxf(pv.z + a2, 0.f);
            r3 = fmaxf(pv.w + a3, 0.f);
        }
        float4 r = { r0, r1, r2, r3 };
        *(float4*)&out[(size_t)node * 64 + c4] = r;
        float dn = dinv[node];
        ushort4 u = { bfb(r0 * dn), bfb(r1 * dn), bfb(r2 * dn), bfb(r3 * dn) };
        *(ushort4*)&outd[(size_t)node * 64 + c4] = u;
    }
}

// ---------------- graph mean pooling (segmented: gid is sorted) ----------------

__global__ __launch_bounds__(256) void k_pool(const float* __restrict__ h, const int* __restrict__ gid,
                                              float* __restrict__ out, float* __restrict__ gcnt, int N) {
    const int CHUNK = 128;
    int wave = blockIdx.x * 4 + (threadIdx.x >> 6);
    int lane = threadIdx.x & 63;
    int beg = wave * CHUNK;
    if (beg >= N) return;
    int end = beg + CHUNK < N ? beg + CHUNK : N;
    int gcur = gid[beg];
    float acc = 0.f;
    int cnt = 0;
    for (int n = beg; n < end; ++n) {
        int g = gid[n];
        float v = h[n * 64 + lane];
        if (g != gcur) {
            atomicAdd(&out[gcur * 64 + lane], acc);
            if (lane == 0) atomicAdd(&gcnt[gcur], (float)cnt);
            gcur = g; acc = 0.f; cnt = 0;
        }
        acc += v;
        ++cnt;
    }
    atomicAdd(&out[gcur * 64 + lane], acc);
    if (lane == 0) atomicAdd(&gcnt[gcur], (float)cnt);
}

__global__ __launch_bounds__(256) void k_div(float* __restrict__ out, const float* __restrict__ gcnt, int total) {
    int i = blockIdx.x * blockDim.x + threadIdx.x;
    if (i < total) out[i] /= fmaxf(gcnt[i >> 6], 1.f);
}

// ---------------- launcher ----------------

extern "C" void kernel_launch(void* const* d_in, const int* in_sizes, int n_in,
                              void* d_out, int out_size, void* d_ws, size_t ws_size,
                              hipStream_t stream) {
    const float* feat = (const float*)d_in[0];
    const int* src = (const int*)d_in[1];
    const int* dst = (const int*)d_in[2];
    const int* gid = (const int*)d_in[3];
    const float* W1 = (const float*)d_in[4];  const float* b1 = (const float*)d_in[5];
    const float* W2 = (const float*)d_in[6];  const float* b2 = (const float*)d_in[7];
    const float* W3 = (const float*)d_in[8];  const float* b3 = (const float*)d_in[9];
    const float* Wt1 = (const float*)d_in[10]; const float* bt1 = (const float*)d_in[11];
    const float* Wp1 = (const float*)d_in[12]; const float* bp1 = (const float*)d_in[13];
    const float* Wt2 = (const float*)d_in[14]; const float* bt2 = (const float*)d_in[15];
    const float* Wp2 = (const float*)d_in[16]; const float* bp2 = (const float*)d_in[17];
    float* out = (float*)d_out;

    const int N = in_sizes[0] / 16;
    const int E = in_sizes[1];
    const int G = out_size / 64;
    const int nb = (N + 255) >> 8;      // buckets (<= 512)

    char* p = (char*)d_ws;
    auto alloc = [&](size_t nbytes) {
        void* r = (void*)p;
        p += (nbytes + 255) & ~(size_t)255;
        return r;
    };
    int* cnt      = (int*)alloc((size_t)N * 4);
    int* row_off  = (int*)alloc((size_t)(N + 1) * 4);
    int* csr      = (int*)alloc((size_t)E * 4);
    int* bsum     = (int*)alloc(512 * 4);
    int* bcnt     = (int*)alloc(512 * 4);
    int* boff     = (int*)alloc(513 * 4);
    int* bcur     = (int*)alloc(512 * 4);
    float* dinv   = (float*)alloc((size_t)N * 4);
    float* bufA   = (float*)alloc((size_t)N * 64 * 4);
    float* bufB   = (float*)alloc((size_t)N * 64 * 4);
    float* bufC   = (float*)alloc((size_t)N * 64 * 4);
    float* bufD   = (float*)alloc((size_t)N * 64 * 4);
    unsigned short* md = (unsigned short*)alloc((size_t)N * 64 * 2);
    float* gcnt   = (float*)alloc((size_t)G * 4);

    unsigned* ebuf = (unsigned*)bufA;   // alias: bufA dead until after CSR build
    unsigned short* hd = (unsigned short*)bufC;
    unsigned short* xd = (unsigned short*)bufC + (size_t)N * 64;

    hipMemsetAsync(bcnt, 0, 512 * 4, stream);
    hipMemsetAsync(gcnt, 0, (size_t)G * 4, stream);
    hipMemsetAsync(d_out, 0, (size_t)out_size * 4, stream);

    const int B = (N + 255) / 256;
    const int nb16 = (N * 16 + 255) / 256;
    const int nbw = (N + 3) / 4;
    const int npool = ((N + 127) / 128 + 3) / 4;
    const int nbt = (N + 63) / 64;
    const int npart = (E + PCHUNK - 1) / PCHUNK;

    // ---- bucketed CSR build v2
    k_bhist<<<256, 256, 0, stream>>>(dst, bcnt, E);
    k_scanBkt<<<1, 512, 0, stream>>>(bcnt, boff, bcur, nb, E);
    k_partA<<<npart, 256, 0, stream>>>(src, dst, bcur, ebuf, E);
    k_cnt<<<nb, 256, 0, stream>>>(ebuf, boff, cnt, N);
    k_scanA<<<B, 256, 0, stream>>>(cnt, bsum, N);
    k_scanB<<<1, 512, 0, stream>>>(bsum, B);
    k_scanC<<<B, 256, 0, stream>>>(cnt, bsum, row_off, dinv, N, E);
    k_scat2<<<nb, 256, 0, stream>>>(ebuf, boff, row_off, csr, N);

    // ---- Cheb layer 1 (IN=16)
    k_feat16<<<nb16, 256, 0, stream>>>(feat, dinv, hd, N * 16);
    k_aggr16<<<nb16, 256, 0, stream>>>(hd, nullptr, dinv, row_off, csr, bufA, xd, -1.f, 0.f, N);
    k_aggr16<<<nb16, 256, 0, stream>>>(xd, feat, dinv, row_off, csr, bufB, nullptr, -2.f, -1.f, N);
    k_cheb_m<16><<<nbt, 256, 0, stream>>>(feat, bufA, bufB, W1, b1, bufC, N);

    // ---- EdgeConv 1
    k_e1_m<<<nbt, 256, 0, stream>>>(bufC, Wt1, Wp1, bt1, bp1, md, bufB, N);
    k_e2_b<<<nbw, 256, 0, stream>>>(md, bufB, row_off, csr, dinv, bufD, hd, N);

    // ---- Cheb layer 2
    k_aggr64<<<nbw, 256, 0, stream>>>(hd, nullptr, dinv, row_off, csr, bufA, xd, -1.f, 0.f, N);
    k_aggr64<<<nbw, 256, 0, stream>>>(xd, bufD, dinv, row_off, csr, bufB, nullptr, -2.f, -1.f, N);
    k_cheb_m<64><<<nbt, 256, 0, stream>>>(bufD, bufA, bufB, W2, b2, bufC, N);

    // ---- EdgeConv 2
    k_e1_m<<<nbt, 256, 0, stream>>>(bufC, Wt2, Wp2, bt2, bp2, md, bufB, N);
    k_e2_b<<<nbw, 256, 0, stream>>>(md, bufB, row_off, csr, dinv, bufD, hd, N);

    // ---- Cheb layer 3
    k_aggr64<<<nbw, 256, 0, stream>>>(hd, nullptr, dinv, row_off, csr, bufA, xd, -1.f, 0.f, N);
    k_aggr64<<<nbw, 256, 0, stream>>>(xd, bufD, dinv, row_off, csr, bufB, nullptr, -2.f, -1.f, N);
    k_cheb_m<64><<<nbt, 256, 0, stream>>>(bufD, bufA, bufB, W3, b3, bufC, N);

    // ---- per-graph mean pooling
    k_pool<<<npool, 256, 0, stream>>>(bufC, gid, out, gcnt, N);
    k_div<<<(out_size + 255) / 256, 256, 0, stream>>>(out, gcnt, out_size);
}

// Round 13
// 655.505 us; speedup vs baseline: 2.2055x; 1.0074x over previous
//
#include <hip/hip_runtime.h>
#include <hip/hip_bf16.h>
#include <math.h>

typedef __attribute__((ext_vector_type(8))) short short8;
typedef __attribute__((ext_vector_type(4))) float floatx4;

__device__ __forceinline__ unsigned short bfb(float x) {
    union { __hip_bfloat16 h; unsigned short u; } c;
    c.h = __float2bfloat16(x);
    return c.u;
}
__device__ __forceinline__ float bf2f(unsigned short u) {
    union { unsigned int i; float f; } c;
    c.i = ((unsigned int)u) << 16;
    return c.f;
}

// ---------------- bucketed CSR build v3 ----------------
// bucket = dst>>8 (256 nodes). ebuf entry = (src<<8)|(dst&255). v3 fuses the whole
// tail (per-node count, node scan, row_off/dinv, scatter) into ONE bucket-parallel
// kernel: row_off inside bucket b = boff[b] + local-LDS-scan — the global node scan
// (4 extra launches + cnt array traffic in v2) was unnecessary.

__global__ __launch_bounds__(256) void k_bhist(const int* __restrict__ dst, int* __restrict__ bcnt, int E) {
    __shared__ int h[512];
    int t = threadIdx.x;
    for (int i = t; i < 512; i += 256) h[i] = 0;
    __syncthreads();
    int step = gridDim.x * 256;
    for (int i = blockIdx.x * 256 + t; i < E; i += step) atomicAdd(&h[dst[i] >> 8], 1);
    __syncthreads();
    for (int i = t; i < 512; i += 256) if (h[i]) atomicAdd(&bcnt[i], h[i]);
}

__global__ __launch_bounds__(512) void k_scanBkt(const int* __restrict__ bcnt, int* __restrict__ boff,
                                                 int* __restrict__ bcur, int nb, int E) {
    __shared__ int s[512];
    int t = threadIdx.x;
    int v = (t < nb) ? bcnt[t] : 0;
    s[t] = v;
    __syncthreads();
    for (int off = 1; off < 512; off <<= 1) {
        int x = (t >= off) ? s[t - off] : 0;
        __syncthreads();
        s[t] += x;
        __syncthreads();
    }
    if (t < nb) { boff[t] = s[t] - v; bcur[t] = s[t] - v; }
    if (t == 0) boff[nb] = E;
}

#define PCHUNK 8192

__global__ __launch_bounds__(256) void k_partA(const int* __restrict__ src, const int* __restrict__ dst,
                                               int* __restrict__ bcur, unsigned* __restrict__ ebuf, int E) {
    __shared__ int h[512];
    __shared__ int base[512];
    int t = threadIdx.x;
    for (int i = t; i < 512; i += 256) h[i] = 0;
    __syncthreads();
    int start = blockIdx.x * PCHUNK;
    int end = start + PCHUNK < E ? start + PCHUNK : E;
    for (int i = start + t; i < end; i += 256) atomicAdd(&h[dst[i] >> 8], 1);
    __syncthreads();
    for (int i = t; i < 512; i += 256) {
        int c = h[i];
        base[i] = c ? atomicAdd(&bcur[i], c) : 0;
        h[i] = 0;
    }
    __syncthreads();
    for (int i = start + t; i < end; i += 256) {
        int d = dst[i];
        int b = d >> 8;
        int r = atomicAdd(&h[b], 1);
        ebuf[base[b] + r] = ((unsigned)src[i] << 8) | (unsigned)(d & 255);
    }
}

__global__ __launch_bounds__(256) void k_finish(const unsigned* __restrict__ ebuf, const int* __restrict__ boff,
                                                int* __restrict__ row_off, float* __restrict__ dinv,
                                                int* __restrict__ csr, int N, int E) {
    __shared__ int h[256];
    __shared__ int sc[256];
    __shared__ int cur[256];
    int b = blockIdx.x, t = threadIdx.x;
    h[t] = 0;
    __syncthreads();
    int beg = boff[b], end = boff[b + 1];
    for (int e = beg + t; e < end; e += 256) atomicAdd(&h[ebuf[e] & 255], 1);
    __syncthreads();
    int v = h[t];
    sc[t] = v;
    __syncthreads();
    for (int off = 1; off < 256; off <<= 1) {
        int x = (t >= off) ? sc[t - off] : 0;
        __syncthreads();
        sc[t] += x;
        __syncthreads();
    }
    int node = (b << 8) + t;
    int excl = beg + sc[t] - v;              // boff[b] + local exclusive scan
    if (node < N) {
        row_off[node] = excl;
        dinv[node] = rsqrtf((float)(v > 1 ? v : 1));
    }
    cur[t] = excl;
    if (b == 0 && t == 0) row_off[N] = E;
    __syncthreads();
    for (int e = beg + t; e < end; e += 256) {   // ebuf span is L2-hot from pass 1
        unsigned ed = ebuf[e];
        int pos = atomicAdd(&cur[ed & 255], 1);
        csr[pos] = (int)(ed >> 8);
    }
}

// ---------------- feat -> bf16 pre-scaled ----------------

__global__ __launch_bounds__(256) void k_feat16(const float* __restrict__ feat, const float* __restrict__ dinv,
                                                unsigned short* __restrict__ featd, int total) {
    int i = blockIdx.x * 256 + threadIdx.x;
    if (i < total) featd[i] = bfb(feat[i] * dinv[i >> 4]);
}

// ---------------- 16-dim Chebyshev aggregation (bf16 gather) ----------------

__global__ __launch_bounds__(256) void k_aggr16(const unsigned short* __restrict__ Xd, const float* __restrict__ Z,
                                                const float* __restrict__ dinv,
                                                const int* __restrict__ row_off, const int* __restrict__ csr,
                                                float* __restrict__ out, unsigned short* __restrict__ outd,
                                                float alpha, float beta, int N) {
    const int D = 16;
    int t = blockIdx.x * blockDim.x + threadIdx.x;
    int node = t / D;
    int d = t % D;
    if (node >= N) return;
    int beg = row_off[node], end = row_off[node + 1];
    float a0 = 0.f, a1 = 0.f, a2 = 0.f, a3 = 0.f;
    int j = beg;
    for (; j + 3 < end; j += 4) {
        int s0 = csr[j], s1 = csr[j + 1], s2 = csr[j + 2], s3 = csr[j + 3];
        a0 += bf2f(Xd[s0 * D + d]);
        a1 += bf2f(Xd[s1 * D + d]);
        a2 += bf2f(Xd[s2 * D + d]);
        a3 += bf2f(Xd[s3 * D + d]);
    }
    for (; j < end; ++j) a0 += bf2f(Xd[csr[j] * D + d]);
    float acc = (a0 + a1) + (a2 + a3);
    float dn = dinv[node];
    float v = alpha * dn * acc;
    if (Z) v += beta * Z[node * D + d];
    out[node * D + d] = v;
    if (outd) outd[node * D + d] = bfb(v * dn);
}

// ---------------- 64-dim Chebyshev aggregation, QUAD-EDGE gather (R12) ----------------

__global__ __launch_bounds__(256) void k_aggr64(const unsigned short* __restrict__ Xd, const float* __restrict__ Z,
                                                const float* __restrict__ dinv,
                                                const int* __restrict__ row_off, const int* __restrict__ csr,
                                                float* __restrict__ out, unsigned short* __restrict__ outd,
                                                float alpha, float beta, int N) {
    int node = blockIdx.x * 4 + (threadIdx.x >> 6);
    if (node >= N) return;
    int lane = threadIdx.x & 63;
    int g = lane >> 4;
    int c4 = (lane & 15) * 4;
    int beg = row_off[node], end = row_off[node + 1];
    float a0 = 0.f, a1 = 0.f, a2 = 0.f, a3 = 0.f;
    float b0 = 0.f, b1 = 0.f, b2 = 0.f, b3 = 0.f;
    int j = beg;
    for (; j + 7 < end; j += 8) {
        int sA = csr[j + g];
        int sB = csr[j + 4 + g];
        ushort4 xA = *(const ushort4*)&Xd[sA * 64 + c4];
        ushort4 xB = *(const ushort4*)&Xd[sB * 64 + c4];
        a0 += bf2f(xA.x); a1 += bf2f(xA.y); a2 += bf2f(xA.z); a3 += bf2f(xA.w);
        b0 += bf2f(xB.x); b1 += bf2f(xB.y); b2 += bf2f(xB.z); b3 += bf2f(xB.w);
    }
    for (; j < end; j += 4) {
        int idx = j + g;
        int s = csr[idx < end ? idx : end - 1];
        ushort4 x = *(const ushort4*)&Xd[s * 64 + c4];
        if (idx < end) {
            a0 += bf2f(x.x); a1 += bf2f(x.y); a2 += bf2f(x.z); a3 += bf2f(x.w);
        }
    }
    a0 += b0; a1 += b1; a2 += b2; a3 += b3;
    a0 += __shfl_xor(a0, 16); a0 += __shfl_xor(a0, 32);
    a1 += __shfl_xor(a1, 16); a1 += __shfl_xor(a1, 32);
    a2 += __shfl_xor(a2, 16); a2 += __shfl_xor(a2, 32);
    a3 += __shfl_xor(a3, 16); a3 += __shfl_xor(a3, 32);
    if (g == 0) {
        float dn = dinv[node];
        float v0 = alpha * dn * a0;
        float v1 = alpha * dn * a1;
        float v2 = alpha * dn * a2;
        float v3 = alpha * dn * a3;
        if (Z) {
            float4 zv = *(const float4*)&Z[(size_t)node * 64 + c4];
            v0 += beta * zv.x; v1 += beta * zv.y; v2 += beta * zv.z; v3 += beta * zv.w;
        }
        float4 r = { v0, v1, v2, v3 };
        *(float4*)&out[(size_t)node * 64 + c4] = r;
        if (outd) {
            ushort4 u = { bfb(v0 * dn), bfb(v1 * dn), bfb(v2 * dn), bfb(v3 * dn) };
            *(ushort4*)&outd[(size_t)node * 64 + c4] = u;
        }
    }
}

// ---------------- Cheb matmul via MFMA 16x16x32 bf16 (R11-verified) ----------------

template <int KDIM>
__global__ __launch_bounds__(256) void k_cheb_m(const float* __restrict__ X0, const float* __restrict__ X1,
                                                const float* __restrict__ X2, const float* __restrict__ W,
                                                const float* __restrict__ b, float* __restrict__ out, int N) {
    constexpr int KT = (KDIM == 16) ? 64 : 3 * KDIM;
    constexpr int SX = KT + 8;
    __shared__ unsigned short Xs[64 * SX];
    __shared__ unsigned short Ws[64 * SX];
    int t = threadIdx.x;

    {
        int sn = t & 63;
        int gn = blockIdx.x * 64 + sn; if (gn >= N) gn = N - 1;
        int k0 = (t >> 6) * (KDIM / 4);
        const float* Xp[3] = { X0, X1, X2 };
#pragma unroll
        for (int a = 0; a < 3; ++a) {
            const float* X = Xp[a];
#pragma unroll
            for (int i = 0; i < KDIM / 16; ++i) {
                float4 v = *(const float4*)&X[(size_t)gn * KDIM + k0 + 4 * i];
                ushort4 u = { bfb(v.x), bfb(v.y), bfb(v.z), bfb(v.w) };
                *(ushort4*)&Xs[sn * SX + a * KDIM + k0 + 4 * i] = u;
            }
        }
        if (KDIM == 16) {
            int kp = 48 + (t >> 6) * 4;
            ushort4 z = { 0, 0, 0, 0 };
            *(ushort4*)&Xs[sn * SX + kp] = z;
        }
    }
    for (int idx = t; idx < 3 * KDIM * 64; idx += 256) {
        int a = idx / (KDIM * 64);
        int r = idx % (KDIM * 64);
        int k = r >> 6, n = r & 63;
        Ws[n * SX + a * KDIM + k] = bfb(W[idx]);
    }
    if (KDIM == 16) {
        for (int idx = t; idx < 1024; idx += 256) {
            int n = idx & 63, k = 48 + (idx >> 6);
            Ws[n * SX + k] = 0;
        }
    }
    __syncthreads();

    int wave = t >> 6, lane = t & 63;
    int fi = lane & 15, quad = lane >> 4;
    int arow = wave * 16 + fi;

    floatx4 acc0 = {0.f,0.f,0.f,0.f}, acc1 = {0.f,0.f,0.f,0.f}, acc2 = {0.f,0.f,0.f,0.f}, acc3 = {0.f,0.f,0.f,0.f};
#pragma unroll
    for (int ks = 0; ks < KT / 32; ++ks) {
        short8 af = *(const short8*)&Xs[arow * SX + ks * 32 + quad * 8];
        short8 b0 = *(const short8*)&Ws[(0 * 16 + fi) * SX + ks * 32 + quad * 8];
        short8 b1 = *(const short8*)&Ws[(1 * 16 + fi) * SX + ks * 32 + quad * 8];
        short8 b2 = *(const short8*)&Ws[(2 * 16 + fi) * SX + ks * 32 + quad * 8];
        short8 b3 = *(const short8*)&Ws[(3 * 16 + fi) * SX + ks * 32 + quad * 8];
        acc0 = __builtin_amdgcn_mfma_f32_16x16x32_bf16(af, b0, acc0, 0, 0, 0);
        acc1 = __builtin_amdgcn_mfma_f32_16x16x32_bf16(af, b1, acc1, 0, 0, 0);
        acc2 = __builtin_amdgcn_mfma_f32_16x16x32_bf16(af, b2, acc2, 0, 0, 0);
        acc3 = __builtin_amdgcn_mfma_f32_16x16x32_bf16(af, b3, acc3, 0, 0, 0);
    }

    int nbase = blockIdx.x * 64 + wave * 16 + quad * 4;
    floatx4 accs[4] = { acc0, acc1, acc2, acc3 };
#pragma unroll
    for (int nt = 0; nt < 4; ++nt) {
        int col = nt * 16 + fi;
        float bias = b[col];
#pragma unroll
        for (int reg = 0; reg < 4; ++reg) {
            int node = nbase + reg;
            if (node < N) out[(size_t)node * 64 + col] = fmaxf(accs[nt][reg] + bias, 0.f);
        }
    }
}

// ---------------- EdgeConv stage 1 via MFMA: [m|p] = X @ [Wt | Wt+Wp] (R11) ----------------

__global__ __launch_bounds__(256) void k_e1_m(const float* __restrict__ X, const float* __restrict__ Wt,
                                              const float* __restrict__ Wp, const float* __restrict__ bt,
                                              const float* __restrict__ bp,
                                              unsigned short* __restrict__ md, float* __restrict__ pbuf, int N) {
    constexpr int SX = 72;
    __shared__ unsigned short Xs[64 * SX];
    __shared__ unsigned short Ws[128 * SX];
    int t = threadIdx.x;

    {
        int sn = t & 63;
        int gn = blockIdx.x * 64 + sn; if (gn >= N) gn = N - 1;
        int k0 = (t >> 6) * 16;
#pragma unroll
        for (int i = 0; i < 4; ++i) {
            float4 v = *(const float4*)&X[(size_t)gn * 64 + k0 + 4 * i];
            ushort4 u = { bfb(v.x), bfb(v.y), bfb(v.z), bfb(v.w) };
            *(ushort4*)&Xs[sn * SX + k0 + 4 * i] = u;
        }
    }
    for (int idx = t; idx < 4096; idx += 256) {
        int k = idx >> 6, n = idx & 63;
        float wt = Wt[idx];
        Ws[n * SX + k] = bfb(wt);
        Ws[(64 + n) * SX + k] = bfb(wt + Wp[idx]);
    }
    __syncthreads();

    int wave = t >> 6, lane = t & 63;
    int fi = lane & 15, quad = lane >> 4;
    int arow = wave * 16 + fi;

    floatx4 acc[8];
#pragma unroll
    for (int i = 0; i < 8; ++i) acc[i] = (floatx4){0.f,0.f,0.f,0.f};
#pragma unroll
    for (int ks = 0; ks < 2; ++ks) {
        short8 af = *(const short8*)&Xs[arow * SX + ks * 32 + quad * 8];
#pragma unroll
        for (int nt = 0; nt < 8; ++nt) {
            short8 bf = *(const short8*)&Ws[(nt * 16 + fi) * SX + ks * 32 + quad * 8];
            acc[nt] = __builtin_amdgcn_mfma_f32_16x16x32_bf16(af, bf, acc[nt], 0, 0, 0);
        }
    }

    int nbase = blockIdx.x * 64 + wave * 16 + quad * 4;
#pragma unroll
    for (int nt = 0; nt < 8; ++nt) {
        int col = nt * 16 + fi;
        if (col < 64) {
#pragma unroll
            for (int reg = 0; reg < 4; ++reg) {
                int node = nbase + reg;
                if (node < N) md[(size_t)node * 64 + col] = bfb(acc[nt][reg]);
            }
        } else {
            int cc = col - 64;
            float bias = bt[cc] + bp[cc];
#pragma unroll
            for (int reg = 0; reg < 4; ++reg) {
                int node = nbase + reg;
                if (node < N) pbuf[(size_t)node * 64 + cc] = acc[nt][reg] + bias;
            }
        }
    }
}

// ---------------- EdgeConv stage 2, QUAD-EDGE bf16 gather (R12) ----------------

__global__ __launch_bounds__(256) void k_e2_b(const unsigned short* __restrict__ md, const float* __restrict__ pbuf,
                                              const int* __restrict__ row_off, const int* __restrict__ csr,
                                              const float* __restrict__ dinv, float* __restrict__ out,
                                              unsigned short* __restrict__ outd, int N) {
    int node = blockIdx.x * 4 + (threadIdx.x >> 6);
    if (node >= N) return;
    int lane = threadIdx.x & 63;
    int g = lane >> 4;
    int c4 = (lane & 15) * 4;
    int beg = row_off[node], end = row_off[node + 1];
    float a0 = -INFINITY, a1 = -INFINITY, a2 = -INFINITY, a3 = -INFINITY;
    float b0 = -INFINITY, b1 = -INFINITY, b2 = -INFINITY, b3 = -INFINITY;
    int j = beg;
    for (; j + 7 < end; j += 8) {
        int sA = csr[j + g];
        int sB = csr[j + 4 + g];
        ushort4 xA = *(const ushort4*)&md[sA * 64 + c4];
        ushort4 xB = *(const ushort4*)&md[sB * 64 + c4];
        a0 = fmaxf(a0, -bf2f(xA.x)); a1 = fmaxf(a1, -bf2f(xA.y));
        a2 = fmaxf(a2, -bf2f(xA.z)); a3 = fmaxf(a3, -bf2f(xA.w));
        b0 = fmaxf(b0, -bf2f(xB.x)); b1 = fmaxf(b1, -bf2f(xB.y));
        b2 = fmaxf(b2, -bf2f(xB.z)); b3 = fmaxf(b3, -bf2f(xB.w));
    }
    for (; j < end; j += 4) {
        int idx = j + g;
        int s = csr[idx < end ? idx : end - 1];
        ushort4 x = *(const ushort4*)&md[s * 64 + c4];
        if (idx < end) {
            a0 = fmaxf(a0, -bf2f(x.x)); a1 = fmaxf(a1, -bf2f(x.y));
            a2 = fmaxf(a2, -bf2f(x.z)); a3 = fmaxf(a3, -bf2f(x.w));
        }
    }
    a0 = fmaxf(a0, b0); a1 = fmaxf(a1, b1); a2 = fmaxf(a2, b2); a3 = fmaxf(a3, b3);
    a0 = fmaxf(a0, __shfl_xor(a0, 16)); a0 = fmaxf(a0, __shfl_xor(a0, 32));
    a1 = fmaxf(a1, __shfl_xor(a1, 16)); a1 = fmaxf(a1, __shfl_xor(a1, 32));
    a2 = fmaxf(a2, __shfl_xor(a2, 16)); a2 = fmaxf(a2, __shfl_xor(a2, 32));
    a3 = fmaxf(a3, __shfl_xor(a3, 16)); a3 = fmaxf(a3, __shfl_xor(a3, 32));
    if (g == 0) {
        float r0 = 0.f, r1 = 0.f, r2 = 0.f, r3 = 0.f;
        if (end > beg) {
            float4 pv = *(const float4*)&pbuf[(size_t)node * 64 + c4];
            r0 = fmaxf(pv.x + a0, 0.f);
            r1 = fmaxf(pv.y + a1, 0.f);
            r2 = fmaxf(pv.z + a2, 0.f);
            r3 = fmaxf(pv.w + a3, 0.f);
        }
        float4 r = { r0, r1, r2, r3 };
        *(float4*)&out[(size_t)node * 64 + c4] = r;
        float dn = dinv[node];
        ushort4 u = { bfb(r0 * dn), bfb(r1 * dn), bfb(r2 * dn), bfb(r3 * dn) };
        *(ushort4*)&outd[(size_t)node * 64 + c4] = u;
    }
}

// ---------------- graph mean pooling (segmented: gid is sorted) ----------------

__global__ __launch_bounds__(256) void k_pool(const float* __restrict__ h, const int* __restrict__ gid,
                                              float* __restrict__ out, float* __restrict__ gcnt, int N) {
    const int CHUNK = 128;
    int wave = blockIdx.x * 4 + (threadIdx.x >> 6);
    int lane = threadIdx.x & 63;
    int beg = wave * CHUNK;
    if (beg >= N) return;
    int end = beg + CHUNK < N ? beg + CHUNK : N;
    int gcur = gid[beg];
    float acc = 0.f;
    int cnt = 0;
    for (int n = beg; n < end; ++n) {
        int g = gid[n];
        float v = h[n * 64 + lane];
        if (g != gcur) {
            atomicAdd(&out[gcur * 64 + lane], acc);
            if (lane == 0) atomicAdd(&gcnt[gcur], (float)cnt);
            gcur = g; acc = 0.f; cnt = 0;
        }
        acc += v;
        ++cnt;
    }
    atomicAdd(&out[gcur * 64 + lane], acc);
    if (lane == 0) atomicAdd(&gcnt[gcur], (float)cnt);
}

__global__ __launch_bounds__(256) void k_div(float* __restrict__ out, const float* __restrict__ gcnt, int total) {
    int i = blockIdx.x * blockDim.x + threadIdx.x;
    if (i < total) out[i] /= fmaxf(gcnt[i >> 6], 1.f);
}

// ---------------- launcher ----------------

extern "C" void kernel_launch(void* const* d_in, const int* in_sizes, int n_in,
                              void* d_out, int out_size, void* d_ws, size_t ws_size,
                              hipStream_t stream) {
    const float* feat = (const float*)d_in[0];
    const int* src = (const int*)d_in[1];
    const int* dst = (const int*)d_in[2];
    const int* gid = (const int*)d_in[3];
    const float* W1 = (const float*)d_in[4];  const float* b1 = (const float*)d_in[5];
    const float* W2 = (const float*)d_in[6];  const float* b2 = (const float*)d_in[7];
    const float* W3 = (const float*)d_in[8];  const float* b3 = (const float*)d_in[9];
    const float* Wt1 = (const float*)d_in[10]; const float* bt1 = (const float*)d_in[11];
    const float* Wp1 = (const float*)d_in[12]; const float* bp1 = (const float*)d_in[13];
    const float* Wt2 = (const float*)d_in[14]; const float* bt2 = (const float*)d_in[15];
    const float* Wp2 = (const float*)d_in[16]; const float* bp2 = (const float*)d_in[17];
    float* out = (float*)d_out;

    const int N = in_sizes[0] / 16;
    const int E = in_sizes[1];
    const int G = out_size / 64;
    const int nb = (N + 255) >> 8;      // buckets (<= 512)

    char* p = (char*)d_ws;
    auto alloc = [&](size_t nbytes) {
        void* r = (void*)p;
        p += (nbytes + 255) & ~(size_t)255;
        return r;
    };
    int* row_off  = (int*)alloc((size_t)(N + 1) * 4);
    int* csr      = (int*)alloc((size_t)E * 4);
    int* bcnt     = (int*)alloc(512 * 4);
    int* boff     = (int*)alloc(513 * 4);
    int* bcur     = (int*)alloc(512 * 4);
    float* dinv   = (float*)alloc((size_t)N * 4);
    float* bufA   = (float*)alloc((size_t)N * 64 * 4);
    float* bufB   = (float*)alloc((size_t)N * 64 * 4);
    float* bufC   = (float*)alloc((size_t)N * 64 * 4);
    float* bufD   = (float*)alloc((size_t)N * 64 * 4);
    unsigned short* md = (unsigned short*)alloc((size_t)N * 64 * 2);
    float* gcnt   = (float*)alloc((size_t)G * 4);

    unsigned* ebuf = (unsigned*)bufA;   // alias: bufA dead until after CSR build
    unsigned short* hd = (unsigned short*)bufC;
    unsigned short* xd = (unsigned short*)bufC + (size_t)N * 64;

    hipMemsetAsync(bcnt, 0, 512 * 4, stream);
    hipMemsetAsync(gcnt, 0, (size_t)G * 4, stream);
    hipMemsetAsync(d_out, 0, (size_t)out_size * 4, stream);

    const int nb16 = (N * 16 + 255) / 256;
    const int nbw = (N + 3) / 4;
    const int npool = ((N + 127) / 128 + 3) / 4;
    const int nbt = (N + 63) / 64;
    const int npart = (E + PCHUNK - 1) / PCHUNK;

    // ---- bucketed CSR build v3 (4 launches)
    k_bhist<<<256, 256, 0, stream>>>(dst, bcnt, E);
    k_scanBkt<<<1, 512, 0, stream>>>(bcnt, boff, bcur, nb, E);
    k_partA<<<npart, 256, 0, stream>>>(src, dst, bcur, ebuf, E);
    k_finish<<<nb, 256, 0, stream>>>(ebuf, boff, row_off, dinv, csr, N, E);

    // ---- Cheb layer 1 (IN=16)
    k_feat16<<<nb16, 256, 0, stream>>>(feat, dinv, hd, N * 16);
    k_aggr16<<<nb16, 256, 0, stream>>>(hd, nullptr, dinv, row_off, csr, bufA, xd, -1.f, 0.f, N);
    k_aggr16<<<nb16, 256, 0, stream>>>(xd, feat, dinv, row_off, csr, bufB, nullptr, -2.f, -1.f, N);
    k_cheb_m<16><<<nbt, 256, 0, stream>>>(feat, bufA, bufB, W1, b1, bufC, N);

    // ---- EdgeConv 1
    k_e1_m<<<nbt, 256, 0, stream>>>(bufC, Wt1, Wp1, bt1, bp1, md, bufB, N);
    k_e2_b<<<nbw, 256, 0, stream>>>(md, bufB, row_off, csr, dinv, bufD, hd, N);

    // ---- Cheb layer 2
    k_aggr64<<<nbw, 256, 0, stream>>>(hd, nullptr, dinv, row_off, csr, bufA, xd, -1.f, 0.f, N);
    k_aggr64<<<nbw, 256, 0, stream>>>(xd, bufD, dinv, row_off, csr, bufB, nullptr, -2.f, -1.f, N);
    k_cheb_m<64><<<nbt, 256, 0, stream>>>(bufD, bufA, bufB, W2, b2, bufC, N);

    // ---- EdgeConv 2
    k_e1_m<<<nbt, 256, 0, stream>>>(bufC, Wt2, Wp2, bt2, bp2, md, bufB, N);
    k_e2_b<<<nbw, 256, 0, stream>>>(md, bufB, row_off, csr, dinv, bufD, hd, N);

    // ---- Cheb layer 3
    k_aggr64<<<nbw, 256, 0, stream>>>(hd, nullptr, dinv, row_off, csr, bufA, xd, -1.f, 0.f, N);
    k_aggr64<<<nbw, 256, 0, stream>>>(xd, bufD, dinv, row_off, csr, bufB, nullptr, -2.f, -1.f, N);
    k_cheb_m<64><<<nbt, 256, 0, stream>>>(bufD, bufA, bufB, W3, b3, bufC, N);

    // ---- per-graph mean pooling
    k_pool<<<npool, 256, 0, stream>>>(bufC, gid, out, gcnt, N);
    k_div<<<(out_size + 255) / 256, 256, 0, stream>>>(out, gcnt, out_size);
}